// Round 1
// baseline (824.893 us; speedup 1.0000x reference)
//
#include <hip/hip_runtime.h>
#include <math.h>

#define Bc 2
#define Nn 2048
#define Hh 256
#define NH 8
#define Dd 32
#define WIN 32
#define WL 65
#define BN (Bc * Nn)   // 4096

// ---------------- Kernel 1: Q,K,V projections ----------------
// grid 256 blocks x 256 thr; each block does 16 rows of (x_scalar @ W + b)
__global__ __launch_bounds__(256) void qkv_kernel(
    const float* __restrict__ x,
    const float* __restrict__ Wq, const float* __restrict__ bq,
    const float* __restrict__ Wk, const float* __restrict__ bk,
    const float* __restrict__ Wv, const float* __restrict__ bv,
    float* __restrict__ Q, float* __restrict__ K, float* __restrict__ V) {
    const int row0 = blockIdx.x * 16;
    const int ch = threadIdx.x;
    __shared__ float xs[16][Hh];
#pragma unroll
    for (int r = 0; r < 16; ++r)
        xs[r][ch] = x[(size_t)(row0 + r) * 1024 + ch];  // x[b,n,0,ch]
    __syncthreads();
    float aq[16], ak[16], av[16];
#pragma unroll
    for (int r = 0; r < 16; ++r) { aq[r] = 0.f; ak[r] = 0.f; av[r] = 0.f; }
    for (int j = 0; j < Hh; ++j) {
        const float wq = Wq[j * Hh + ch];
        const float wk = Wk[j * Hh + ch];
        const float wv = Wv[j * Hh + ch];
#pragma unroll
        for (int r = 0; r < 16; ++r) {
            const float xv = xs[r][j];
            aq[r] = fmaf(xv, wq, aq[r]);
            ak[r] = fmaf(xv, wk, ak[r]);
            av[r] = fmaf(xv, wv, av[r]);
        }
    }
    const float bqv = bq[ch], bkv = bk[ch], bvv = bv[ch];
#pragma unroll
    for (int r = 0; r < 16; ++r) {
        const int row = row0 + r;
        Q[(size_t)row * Hh + ch] = aq[r] + bqv;
        K[(size_t)row * Hh + ch] = ak[r] + bkv;
        V[(size_t)row * Hh + ch] = av[r] + bvv;
    }
}

// ---------------- Kernel 2: vec_proj -> vec_dot, vec_norm ----------------
// grid 512 blocks x 256 thr; each block does 8 rows
__global__ __launch_bounds__(256) void vec_kernel(
    const float* __restrict__ x, const float* __restrict__ Wvec,
    float* __restrict__ vec_dot, float* __restrict__ vec_norm) {
    const int row0 = blockIdx.x * 8;
    const int ch = threadIdx.x;
    __shared__ float vs[8][3][Hh];
#pragma unroll
    for (int r = 0; r < 8; ++r)
#pragma unroll
        for (int c = 0; c < 3; ++c)
            vs[r][c][ch] = x[(size_t)(row0 + r) * 1024 + (1 + c) * Hh + ch];
    __syncthreads();
    float a1[8][3], a2[8][3];
#pragma unroll
    for (int r = 0; r < 8; ++r)
#pragma unroll
        for (int c = 0; c < 3; ++c) { a1[r][c] = 0.f; a2[r][c] = 0.f; }
    for (int j = 0; j < Hh; ++j) {
        const float w1 = Wvec[j * 512 + ch];
        const float w2 = Wvec[j * 512 + Hh + ch];
#pragma unroll
        for (int r = 0; r < 8; ++r) {
#pragma unroll
            for (int c = 0; c < 3; ++c) {
                const float vv = vs[r][c][j];
                a1[r][c] = fmaf(vv, w1, a1[r][c]);
                a2[r][c] = fmaf(vv, w2, a2[r][c]);
            }
        }
    }
#pragma unroll
    for (int r = 0; r < 8; ++r) {
        const int row = row0 + r;
        float dot = 0.f;
#pragma unroll
        for (int c = 0; c < 3; ++c) dot += a1[r][c] * a2[r][c];
        vec_dot[(size_t)row * Hh + ch] = dot;
        const float v0 = vs[r][0][ch], v1 = vs[r][1][ch], v2 = vs[r][2][ch];
        vec_norm[(size_t)row * Hh + ch] = sqrtf(v0 * v0 + v1 * v1 + v2 * v2);
    }
}

// ---------------- Kernel 3: gate = sigmoid(invariants @ Wg + bg) ----------------
// grid 256 blocks x 256 thr; each block does 16 rows, K=512
__global__ __launch_bounds__(256) void gate_kernel(
    const float* __restrict__ vec_dot, const float* __restrict__ vec_norm,
    const float* __restrict__ alpha_dot, const float* __restrict__ alpha_norm,
    const float* __restrict__ Wg, const float* __restrict__ bg,
    float* __restrict__ gate) {
    const int row0 = blockIdx.x * 16;
    const int ch = threadIdx.x;
    __shared__ float inv[16][512];
    const float ad = alpha_dot[0], an = alpha_norm[0];
#pragma unroll
    for (int r = 0; r < 16; ++r) {
        const int row = row0 + r;
        inv[r][ch] = ad * vec_dot[(size_t)row * Hh + ch];
        inv[r][Hh + ch] = an * vec_norm[(size_t)row * Hh + ch];
    }
    __syncthreads();
    float acc[16];
#pragma unroll
    for (int r = 0; r < 16; ++r) acc[r] = 0.f;
    for (int j = 0; j < 512; ++j) {
        const float w = Wg[j * Hh + ch];
#pragma unroll
        for (int r = 0; r < 16; ++r) acc[r] = fmaf(inv[r][j], w, acc[r]);
    }
    const float b = bg[ch];
#pragma unroll
    for (int r = 0; r < 16; ++r) {
        const float z = acc[r] + b;
        gate[(size_t)(row0 + r) * Hh + ch] = 1.f / (1.f + expf(-z));
    }
}

// ---------------- Kernel 4: windowed attention ----------------
// one block (128 thr) per (b, head, i); 32768 blocks
__global__ __launch_bounds__(128) void attn_kernel(
    const float* __restrict__ x,
    const float* __restrict__ Q, const float* __restrict__ K,
    const float* __restrict__ V,
    float* __restrict__ attnw, float* __restrict__ x_agg,
    float* __restrict__ vec_aggr) {
    const int pos = blockIdx.x;
    const int i = pos & (Nn - 1);
    const int bh = pos >> 11;       // N=2048
    const int b = bh >> 3;
    const int hd = bh & 7;
    const int tid = threadIdx.x;

    __shared__ float qv[Dd];
    __shared__ float p[WL];
    __shared__ float red;

    if (tid < Dd)
        qv[tid] = Q[((size_t)(b * Nn + i)) * Hh + hd * Dd + tid];
    __syncthreads();

    if (tid < WL) {
        const int j = i - WIN + tid;
        float s = 0.f;
        if (j >= 0 && j < Nn) {
            const float* kp = &K[((size_t)(b * Nn + j)) * Hh + hd * Dd];
#pragma unroll
            for (int d2 = 0; d2 < Dd; ++d2) s = fmaf(qv[d2], kp[d2], s);
            s *= 0.17677669529663687f;  // 1/sqrt(32)
        }
        p[tid] = s;  // padded entries keep score 0 (matches zero-padded k)
    }
    __syncthreads();

    if (tid == 0) {
        float m = -1e30f;
        for (int w = 0; w < WL; ++w) m = fmaxf(m, p[w]);
        float sum = 0.f;
        for (int w = 0; w < WL; ++w) {
            const float e = expf(p[w] - m);
            p[w] = e;
            sum += e;
        }
        red = 1.f / sum;
    }
    __syncthreads();

    if (tid < WL) {
        const float pw = p[tid] * red;
        p[tid] = pw;
        attnw[(size_t)bh * Nn * WL + (size_t)i * WL + tid] = pw;
    }
    __syncthreads();

    float acc = 0.f;
    if (tid < Dd) {
        for (int w = 0; w < WL; ++w) {
            const int j = i - WIN + w;
            if (j >= 0 && j < Nn)
                acc = fmaf(p[w], V[((size_t)(b * Nn + j)) * Hh + hd * Dd + tid], acc);
        }
        x_agg[((size_t)bh * Nn + i) * Dd + tid] = acc;
    } else {
        const int t = tid - Dd;
        const int c = t >> 5;
        const int dd = t & 31;
        for (int w = 0; w < WL; ++w) {
            const int j = i - WIN + w;
            if (j >= 0 && j < Nn)
                acc = fmaf(p[w],
                           x[((size_t)(b * Nn + j)) * 1024 + (1 + c) * Hh + hd * Dd + dd],
                           acc);
        }
        vec_aggr[(((size_t)bh * Nn + i) * 3 + c) * Dd + dd] = acc;
    }
}

// ---------------- Kernel 5: output projection + combine ----------------
// grid 512 blocks x 256 thr; each block does 8 rows; each thread owns o1/o2/o3[ch]
__global__ __launch_bounds__(256) void out_kernel(
    const float* __restrict__ x,
    const float* __restrict__ Wo, const float* __restrict__ bo,
    const float* __restrict__ vec_dot, const float* __restrict__ vec_norm,
    const float* __restrict__ gate, const float* __restrict__ x_agg,
    const float* __restrict__ vec_aggr, float* __restrict__ out) {
    const int row0 = blockIdx.x * 8;
    const int ch = threadIdx.x;
    const int hd = ch >> 5;
    const int dd = ch & 31;
    __shared__ float xo[8][Hh];
#pragma unroll
    for (int r = 0; r < 8; ++r) {
        const int row = row0 + r;
        const int b = row >> 11;
        const int n = row & (Nn - 1);
        xo[r][ch] = x_agg[(((size_t)(b * NH + hd)) * Nn + n) * Dd + dd];
    }
    __syncthreads();
    float a1[8], a2[8], a3[8];
#pragma unroll
    for (int r = 0; r < 8; ++r) { a1[r] = 0.f; a2[r] = 0.f; a3[r] = 0.f; }
    for (int j = 0; j < Hh; ++j) {
        const float w1 = Wo[j * 768 + ch];
        const float w2 = Wo[j * 768 + Hh + ch];
        const float w3 = Wo[j * 768 + 512 + ch];
#pragma unroll
        for (int r = 0; r < 8; ++r) {
            const float xv = xo[r][j];
            a1[r] = fmaf(xv, w1, a1[r]);
            a2[r] = fmaf(xv, w2, a2[r]);
            a3[r] = fmaf(xv, w3, a3[r]);
        }
    }
    const float b1 = bo[ch], b2 = bo[Hh + ch], b3 = bo[512 + ch];
#pragma unroll
    for (int r = 0; r < 8; ++r) {
        const int row = row0 + r;
        const int b = row >> 11;
        const int n = row & (Nn - 1);
        const float vd = vec_dot[(size_t)row * Hh + ch];
        const float vn = vec_norm[(size_t)row * Hh + ch];
        const float o1 = a1[r] + b1, o2 = a2[r] + b2, o3 = a3[r] + b3;
        out[(size_t)row * 1024 + ch] = vd * o1 + vn * o2 + o3;
        const float g = gate[(size_t)row * Hh + ch];
        const size_t vabase = (((size_t)(b * NH + hd)) * Nn + n) * 96 + dd;
#pragma unroll
        for (int c = 0; c < 3; ++c) {
            const float va = vec_aggr[vabase + c * Dd];
            const float vv = x[(size_t)row * 1024 + (1 + c) * Hh + ch];
            out[(size_t)row * 1024 + (1 + c) * Hh + ch] = g * va + vv;
        }
    }
}

extern "C" void kernel_launch(void* const* d_in, const int* in_sizes, int n_in,
                              void* d_out, int out_size, void* d_ws, size_t ws_size,
                              hipStream_t stream) {
    const float* x  = (const float*)d_in[0];
    const float* Wq = (const float*)d_in[1];
    const float* bq = (const float*)d_in[2];
    const float* Wk = (const float*)d_in[3];
    const float* bk = (const float*)d_in[4];
    const float* Wv = (const float*)d_in[5];
    const float* bv = (const float*)d_in[6];
    const float* Wo = (const float*)d_in[7];
    const float* bo = (const float*)d_in[8];
    const float* Wvec = (const float*)d_in[9];
    const float* alpha_dot  = (const float*)d_in[10];
    const float* alpha_norm = (const float*)d_in[11];
    const float* Wg = (const float*)d_in[12];
    const float* bg = (const float*)d_in[13];

    float* ws = (float*)d_ws;
    float* Q        = ws;
    float* K        = ws + 1048576;
    float* V        = ws + 2097152;
    float* vec_dot  = ws + 3145728;
    float* vec_norm = ws + 4194304;
    float* gate     = ws + 5242880;
    float* x_agg    = ws + 6291456;
    float* vec_aggr = ws + 7340032;  // size 3145728; total 10,485,760 floats (~42 MB)

    float* out = (float*)d_out;
    float* attnw = out + (size_t)Bc * Nn * 4 * Hh;  // 4,194,304

    qkv_kernel<<<256, 256, 0, stream>>>(x, Wq, bq, Wk, bk, Wv, bv, Q, K, V);
    vec_kernel<<<512, 256, 0, stream>>>(x, Wvec, vec_dot, vec_norm);
    gate_kernel<<<256, 256, 0, stream>>>(vec_dot, vec_norm, alpha_dot, alpha_norm,
                                         Wg, bg, gate);
    attn_kernel<<<32768, 128, 0, stream>>>(x, Q, K, V, attnw, x_agg, vec_aggr);
    out_kernel<<<512, 256, 0, stream>>>(x, Wo, bo, vec_dot, vec_norm, gate,
                                        x_agg, vec_aggr, out);
}

// Round 2
// 306.638 us; speedup vs baseline: 2.6901x; 2.6901x over previous
//
#include <hip/hip_runtime.h>
#include <math.h>

#define Bc 2
#define Nn 2048
#define Hh 256
#define NH 8
#define Dd 32
#define WIN 32
#define WL 65
#define BN (Bc * Nn)   // 4096

// ---------------- Kernel 1: Q,K,V projections ----------------
// grid 512 blocks x 256 thr; each block does 8 rows of (x_scalar @ W + b)
__global__ __launch_bounds__(256) void qkv_kernel(
    const float* __restrict__ x,
    const float* __restrict__ Wq, const float* __restrict__ bq,
    const float* __restrict__ Wk, const float* __restrict__ bk,
    const float* __restrict__ Wv, const float* __restrict__ bv,
    float* __restrict__ Q, float* __restrict__ K, float* __restrict__ V) {
    const int row0 = blockIdx.x * 8;
    const int ch = threadIdx.x;
    __shared__ float xs[8][Hh];
#pragma unroll
    for (int r = 0; r < 8; ++r)
        xs[r][ch] = x[(size_t)(row0 + r) * 1024 + ch];  // x[b,n,0,ch]
    __syncthreads();
    float aq[8], ak[8], av[8];
#pragma unroll
    for (int r = 0; r < 8; ++r) { aq[r] = 0.f; ak[r] = 0.f; av[r] = 0.f; }
    for (int j = 0; j < Hh; ++j) {
        const float wq = Wq[j * Hh + ch];
        const float wk = Wk[j * Hh + ch];
        const float wv = Wv[j * Hh + ch];
#pragma unroll
        for (int r = 0; r < 8; ++r) {
            const float xv = xs[r][j];
            aq[r] = fmaf(xv, wq, aq[r]);
            ak[r] = fmaf(xv, wk, ak[r]);
            av[r] = fmaf(xv, wv, av[r]);
        }
    }
    const float bqv = bq[ch], bkv = bk[ch], bvv = bv[ch];
#pragma unroll
    for (int r = 0; r < 8; ++r) {
        const int row = row0 + r;
        Q[(size_t)row * Hh + ch] = aq[r] + bqv;
        K[(size_t)row * Hh + ch] = ak[r] + bkv;
        V[(size_t)row * Hh + ch] = av[r] + bvv;
    }
}

// ---------------- Kernel 2: vec_proj -> vec_dot, vec_norm ----------------
// grid 512 blocks x 256 thr; each block does 8 rows
__global__ __launch_bounds__(256) void vec_kernel(
    const float* __restrict__ x, const float* __restrict__ Wvec,
    float* __restrict__ vec_dot, float* __restrict__ vec_norm) {
    const int row0 = blockIdx.x * 8;
    const int ch = threadIdx.x;
    __shared__ float vs[8][3][Hh];
#pragma unroll
    for (int r = 0; r < 8; ++r)
#pragma unroll
        for (int c = 0; c < 3; ++c)
            vs[r][c][ch] = x[(size_t)(row0 + r) * 1024 + (1 + c) * Hh + ch];
    __syncthreads();
    float a1[8][3], a2[8][3];
#pragma unroll
    for (int r = 0; r < 8; ++r)
#pragma unroll
        for (int c = 0; c < 3; ++c) { a1[r][c] = 0.f; a2[r][c] = 0.f; }
    for (int j = 0; j < Hh; ++j) {
        const float w1 = Wvec[j * 512 + ch];
        const float w2 = Wvec[j * 512 + Hh + ch];
#pragma unroll
        for (int r = 0; r < 8; ++r) {
#pragma unroll
            for (int c = 0; c < 3; ++c) {
                const float vv = vs[r][c][j];
                a1[r][c] = fmaf(vv, w1, a1[r][c]);
                a2[r][c] = fmaf(vv, w2, a2[r][c]);
            }
        }
    }
#pragma unroll
    for (int r = 0; r < 8; ++r) {
        const int row = row0 + r;
        float dot = 0.f;
#pragma unroll
        for (int c = 0; c < 3; ++c) dot += a1[r][c] * a2[r][c];
        vec_dot[(size_t)row * Hh + ch] = dot;
        const float v0 = vs[r][0][ch], v1 = vs[r][1][ch], v2 = vs[r][2][ch];
        vec_norm[(size_t)row * Hh + ch] = sqrtf(v0 * v0 + v1 * v1 + v2 * v2);
    }
}

// ---------------- Kernel 3: gate = sigmoid(invariants @ Wg + bg) ----------------
// grid 512 blocks x 256 thr; each block does 8 rows, K=512
__global__ __launch_bounds__(256) void gate_kernel(
    const float* __restrict__ vec_dot, const float* __restrict__ vec_norm,
    const float* __restrict__ alpha_dot, const float* __restrict__ alpha_norm,
    const float* __restrict__ Wg, const float* __restrict__ bg,
    float* __restrict__ gate) {
    const int row0 = blockIdx.x * 8;
    const int ch = threadIdx.x;
    __shared__ float inv[8][512];
    const float ad = alpha_dot[0], an = alpha_norm[0];
#pragma unroll
    for (int r = 0; r < 8; ++r) {
        const int row = row0 + r;
        inv[r][ch] = ad * vec_dot[(size_t)row * Hh + ch];
        inv[r][Hh + ch] = an * vec_norm[(size_t)row * Hh + ch];
    }
    __syncthreads();
    float acc[8];
#pragma unroll
    for (int r = 0; r < 8; ++r) acc[r] = 0.f;
    for (int j = 0; j < 512; ++j) {
        const float w = Wg[j * Hh + ch];
#pragma unroll
        for (int r = 0; r < 8; ++r) acc[r] = fmaf(inv[r][j], w, acc[r]);
    }
    const float b = bg[ch];
#pragma unroll
    for (int r = 0; r < 8; ++r) {
        const float z = acc[r] + b;
        gate[(size_t)(row0 + r) * Hh + ch] = 1.f / (1.f + __expf(-z));
    }
}

// ---------------- Kernel 4a: windowed attention scores + softmax ----------------
// one block (256 thr) per (bh, tile of 32 positions); 1024 blocks
// 8 lanes per position; shuffle softmax; writes normalized weights to attnw.
__global__ __launch_bounds__(256) void attn_score_kernel(
    const float* __restrict__ Q, const float* __restrict__ K,
    float* __restrict__ attnw) {
    const int bh = blockIdx.x >> 6;
    const int tile = blockIdx.x & 63;
    const int b = bh >> 3, hd = bh & 7;
    const int i0 = tile * 32;
    const int t = threadIdx.x;

    __shared__ float Qs[32][36];   // 36-stride: 16B aligned + bank spread
    __shared__ float Ks[96][36];

    // stage Q: 32 rows x 8 float4
    {
        const int row = t >> 3, c4 = t & 7;
        const float4 qv = *(const float4*)&Q[((size_t)(b * Nn + i0 + row)) * Hh + hd * Dd + 4 * c4];
        *(float4*)&Qs[row][4 * c4] = qv;
    }
    // stage K: 96 rows x 8 float4 (halo +-32, OOB rows -> 0 so score==0, matching zero-pad)
#pragma unroll
    for (int kk = 0; kk < 3; ++kk) {
        const int idx = t + kk * 256;
        const int row = idx >> 3, c4 = idx & 7;
        const int j = i0 - WIN + row;
        float4 kv = make_float4(0.f, 0.f, 0.f, 0.f);
        if (j >= 0 && j < Nn)
            kv = *(const float4*)&K[((size_t)(b * Nn + j)) * Hh + hd * Dd + 4 * c4];
        *(float4*)&Ks[row][4 * c4] = kv;
    }
    __syncthreads();

    const int i = t >> 3, sub = t & 7;
    float4 qr[8];
#pragma unroll
    for (int c = 0; c < 8; ++c) qr[c] = *(const float4*)&Qs[i][4 * c];

    float s[9];
#pragma unroll
    for (int k = 0; k < 9; ++k) {
        const int w = sub + 8 * k;
        if (w <= 64) {
            const int row = i + w;
            float dot = 0.f;
#pragma unroll
            for (int c = 0; c < 8; ++c) {
                const float4 kv = *(const float4*)&Ks[row][4 * c];
                dot = fmaf(qr[c].x, kv.x, dot);
                dot = fmaf(qr[c].y, kv.y, dot);
                dot = fmaf(qr[c].z, kv.z, dot);
                dot = fmaf(qr[c].w, kv.w, dot);
            }
            s[k] = dot * 0.17677669529663687f;  // 1/sqrt(32)
        } else {
            s[k] = -1e30f;
        }
    }
    float m = s[0];
#pragma unroll
    for (int k = 1; k < 9; ++k) m = fmaxf(m, s[k]);
#pragma unroll
    for (int off = 1; off < 8; off <<= 1) m = fmaxf(m, __shfl_xor(m, off, 64));
    float sum = 0.f;
#pragma unroll
    for (int k = 0; k < 9; ++k) {
        const float e = (sub + 8 * k <= 64) ? __expf(s[k] - m) : 0.f;
        s[k] = e;
        sum += e;
    }
#pragma unroll
    for (int off = 1; off < 8; off <<= 1) sum += __shfl_xor(sum, off, 64);
    const float inv = 1.f / sum;
    float* dst = &attnw[((size_t)bh * Nn + (i0 + i)) * WL];
#pragma unroll
    for (int k = 0; k < 9; ++k) {
        const int w = sub + 8 * k;
        if (w <= 64) dst[w] = s[k] * inv;
    }
}

// ---------------- Kernel 4b: weighted aggregation of V + vec ----------------
// one block (256 thr) per (bh, tile of 32 positions); 1024 blocks
// Ss rows: 128 value dims (0..31 = V, 32..127 = vec c*32+dd), padded to 132.
// Register tile: 4 i x 4 dims per thread -> each Ss float4 read once per 4 outputs.
__global__ __launch_bounds__(256) void attn_agg_kernel(
    const float* __restrict__ x, const float* __restrict__ V,
    const float* __restrict__ attnw,
    float* __restrict__ x_agg, float* __restrict__ vec_aggr) {
    const int bh = blockIdx.x >> 6;
    const int tile = blockIdx.x & 63;
    const int b = bh >> 3, hd = bh & 7;
    const int i0 = tile * 32;
    const int t = threadIdx.x;

    __shared__ float Ss[96][132];  // 50.7 KB
    __shared__ float Pl[32][72];   // w+3 index, zero-padded edges; 9.2 KB

    // stage values: 96 rows x 32 float4
#pragma unroll
    for (int kk = 0; kk < 12; ++kk) {
        const int idx = t + kk * 256;
        const int row = idx >> 5, c4 = idx & 31;
        const int j = i0 - WIN + row;
        float4 val = make_float4(0.f, 0.f, 0.f, 0.f);
        if (j >= 0 && j < Nn) {
            if (c4 < 8) {
                val = *(const float4*)&V[((size_t)(b * Nn + j)) * Hh + hd * Dd + 4 * c4];
            } else {
                const int cc = (c4 - 8) >> 3, s4 = c4 & 7;
                val = *(const float4*)&x[((size_t)(b * Nn + j)) * 1024 + (1 + cc) * Hh + hd * Dd + 4 * s4];
            }
        }
        *(float4*)&Ss[row][4 * c4] = val;
    }
    // stage P with zero pads at w+3 in {0,1,2} and {68..71}
    {
        const int i = t >> 3, sub = t & 7;
        const float* src = &attnw[((size_t)bh * Nn + (i0 + i)) * WL];
#pragma unroll
        for (int k = 0; k < 9; ++k) {
            const int w = sub + 8 * k;
            if (w <= 64) Pl[i][w + 3] = src[w];
        }
        if (sub == 0) {
            Pl[i][0] = 0.f; Pl[i][1] = 0.f; Pl[i][2] = 0.f;
            Pl[i][68] = 0.f; Pl[i][69] = 0.f; Pl[i][70] = 0.f; Pl[i][71] = 0.f;
        }
    }
    __syncthreads();

    const int c4 = t & 31, itile = t >> 5;
    float4 acc[4];
#pragma unroll
    for (int ii = 0; ii < 4; ++ii) acc[ii] = make_float4(0.f, 0.f, 0.f, 0.f);
#pragma unroll 4
    for (int jj = 0; jj < 68; ++jj) {
        const int row = itile * 4 + jj;
        const float4 sv = *(const float4*)&Ss[row][4 * c4];
#pragma unroll
        for (int ii = 0; ii < 4; ++ii) {
            const float p = Pl[itile * 4 + ii][jj - ii + 3];
            acc[ii].x = fmaf(p, sv.x, acc[ii].x);
            acc[ii].y = fmaf(p, sv.y, acc[ii].y);
            acc[ii].z = fmaf(p, sv.z, acc[ii].z);
            acc[ii].w = fmaf(p, sv.w, acc[ii].w);
        }
    }
#pragma unroll
    for (int ii = 0; ii < 4; ++ii) {
        const int i = i0 + itile * 4 + ii;
        if (c4 < 8) {
            *(float4*)&x_agg[((size_t)bh * Nn + i) * Dd + 4 * c4] = acc[ii];
        } else {
            const int cc = (c4 - 8) >> 3, s4 = c4 & 7;
            *(float4*)&vec_aggr[(((size_t)bh * Nn + i) * 3 + cc) * Dd + 4 * s4] = acc[ii];
        }
    }
}

// ---------------- Kernel 5: output projection + combine ----------------
// grid 512 blocks x 256 thr; each block does 8 rows; each thread owns o1/o2/o3[ch]
__global__ __launch_bounds__(256) void out_kernel(
    const float* __restrict__ x,
    const float* __restrict__ Wo, const float* __restrict__ bo,
    const float* __restrict__ vec_dot, const float* __restrict__ vec_norm,
    const float* __restrict__ gate, const float* __restrict__ x_agg,
    const float* __restrict__ vec_aggr, float* __restrict__ out) {
    const int row0 = blockIdx.x * 8;
    const int ch = threadIdx.x;
    const int hd = ch >> 5;
    const int dd = ch & 31;
    __shared__ float xo[8][Hh];
#pragma unroll
    for (int r = 0; r < 8; ++r) {
        const int row = row0 + r;
        const int b = row >> 11;
        const int n = row & (Nn - 1);
        xo[r][ch] = x_agg[(((size_t)(b * NH + hd)) * Nn + n) * Dd + dd];
    }
    __syncthreads();
    float a1[8], a2[8], a3[8];
#pragma unroll
    for (int r = 0; r < 8; ++r) { a1[r] = 0.f; a2[r] = 0.f; a3[r] = 0.f; }
    for (int j = 0; j < Hh; ++j) {
        const float w1 = Wo[j * 768 + ch];
        const float w2 = Wo[j * 768 + Hh + ch];
        const float w3 = Wo[j * 768 + 512 + ch];
#pragma unroll
        for (int r = 0; r < 8; ++r) {
            const float xv = xo[r][j];
            a1[r] = fmaf(xv, w1, a1[r]);
            a2[r] = fmaf(xv, w2, a2[r]);
            a3[r] = fmaf(xv, w3, a3[r]);
        }
    }
    const float b1 = bo[ch], b2 = bo[Hh + ch], b3 = bo[512 + ch];
#pragma unroll
    for (int r = 0; r < 8; ++r) {
        const int row = row0 + r;
        const int b = row >> 11;
        const int n = row & (Nn - 1);
        const float vd = vec_dot[(size_t)row * Hh + ch];
        const float vn = vec_norm[(size_t)row * Hh + ch];
        const float o1 = a1[r] + b1, o2 = a2[r] + b2, o3 = a3[r] + b3;
        out[(size_t)row * 1024 + ch] = vd * o1 + vn * o2 + o3;
        const float g = gate[(size_t)row * Hh + ch];
        const size_t vabase = (((size_t)(b * NH + hd)) * Nn + n) * 96 + dd;
#pragma unroll
        for (int c = 0; c < 3; ++c) {
            const float va = vec_aggr[vabase + c * Dd];
            const float vv = x[(size_t)row * 1024 + (1 + c) * Hh + ch];
            out[(size_t)row * 1024 + (1 + c) * Hh + ch] = g * va + vv;
        }
    }
}

extern "C" void kernel_launch(void* const* d_in, const int* in_sizes, int n_in,
                              void* d_out, int out_size, void* d_ws, size_t ws_size,
                              hipStream_t stream) {
    const float* x  = (const float*)d_in[0];
    const float* Wq = (const float*)d_in[1];
    const float* bq = (const float*)d_in[2];
    const float* Wk = (const float*)d_in[3];
    const float* bk = (const float*)d_in[4];
    const float* Wv = (const float*)d_in[5];
    const float* bv = (const float*)d_in[6];
    const float* Wo = (const float*)d_in[7];
    const float* bo = (const float*)d_in[8];
    const float* Wvec = (const float*)d_in[9];
    const float* alpha_dot  = (const float*)d_in[10];
    const float* alpha_norm = (const float*)d_in[11];
    const float* Wg = (const float*)d_in[12];
    const float* bg = (const float*)d_in[13];

    float* ws = (float*)d_ws;
    float* Q        = ws;
    float* K        = ws + 1048576;
    float* V        = ws + 2097152;
    float* vec_dot  = ws + 3145728;
    float* vec_norm = ws + 4194304;
    float* gate     = ws + 5242880;
    float* x_agg    = ws + 6291456;
    float* vec_aggr = ws + 7340032;  // size 3145728; total 10,485,760 floats (~42 MB)

    float* out = (float*)d_out;
    float* attnw = out + (size_t)Bc * Nn * 4 * Hh;  // 4,194,304

    qkv_kernel<<<512, 256, 0, stream>>>(x, Wq, bq, Wk, bk, Wv, bv, Q, K, V);
    vec_kernel<<<512, 256, 0, stream>>>(x, Wvec, vec_dot, vec_norm);
    gate_kernel<<<512, 256, 0, stream>>>(vec_dot, vec_norm, alpha_dot, alpha_norm,
                                         Wg, bg, gate);
    attn_score_kernel<<<1024, 256, 0, stream>>>(Q, K, attnw);
    attn_agg_kernel<<<1024, 256, 0, stream>>>(x, V, attnw, x_agg, vec_aggr);
    out_kernel<<<512, 256, 0, stream>>>(x, Wo, bo, vec_dot, vec_norm, gate,
                                        x_agg, vec_aggr, out);
}

// Round 3
// 186.489 us; speedup vs baseline: 4.4233x; 1.6443x over previous
//
#include <hip/hip_runtime.h>
#include <math.h>

#define Bc 2
#define Nn 2048
#define Hh 256
#define NH 8
#define Dd 32
#define WIN 32
#define WL 65
#define BN (Bc * Nn)   // 4096

typedef __attribute__((ext_vector_type(8))) short bf16x8;
typedef __attribute__((ext_vector_type(4))) float f32x4;

__device__ inline short f2bf(float f) {
    union { float f; unsigned u; } v; v.f = f;
    unsigned r = v.u + 0x7fffu + ((v.u >> 16) & 1u);
    return (short)(r >> 16);
}

// ---------------- cast x -> bf16 (xs_bf 4096x256, vec_bf 12288x256) ----------------
__global__ __launch_bounds__(256) void castx_kernel(
    const float* __restrict__ x, short* __restrict__ xs_bf, short* __restrict__ vec_bf) {
#pragma unroll
    for (int it = 0; it < 8; ++it) {
        const int e = it * 524288 + blockIdx.x * 256 + threadIdx.x;
        const int bn = e >> 10, sub = (e >> 8) & 3, ch = e & 255;
        const short v = f2bf(x[e]);
        if (sub == 0) xs_bf[bn * 256 + ch] = v;
        else vec_bf[(bn * 3 + sub - 1) * 256 + ch] = v;
    }
}

// ---------------- cast + transpose weights -> bf16 B^T (N x K) ----------------
__global__ __launch_bounds__(256) void castw_kernel(
    const float* __restrict__ Wq, const float* __restrict__ Wk, const float* __restrict__ Wv,
    const float* __restrict__ Wvec, const float* __restrict__ Wg, const float* __restrict__ Wo,
    short* __restrict__ WqkvT, short* __restrict__ WvecT,
    short* __restrict__ WgT, short* __restrict__ WoT) {
    __shared__ float Ts[32][33];
    const int t = threadIdx.x;
    const int cc = t & 31, r0 = t >> 5;
    const int id = blockIdx.x;
    const float* W; int ldw; short* WT; int ldwt; int n0s, k0, n0d;
    if (id < 192) {            // [Wq|Wk|Wv] 256x768 -> WqkvT 768x256
        const int tn = id >> 3, tk = id & 7, sel = tn >> 3;
        W = sel == 0 ? Wq : (sel == 1 ? Wk : Wv); ldw = 256;
        n0s = (tn & 7) * 32; k0 = tk * 32; WT = WqkvT; ldwt = 256; n0d = tn * 32;
    } else if (id < 320) {     // Wvec 256x512 -> WvecT 512x256
        const int id2 = id - 192, tn = id2 >> 3, tk = id2 & 7;
        W = Wvec; ldw = 512; n0s = tn * 32; k0 = tk * 32; WT = WvecT; ldwt = 256; n0d = n0s;
    } else if (id < 448) {     // Wg 512x256 -> WgT 256x512
        const int id3 = id - 320, tn = id3 >> 4, tk = id3 & 15;
        W = Wg; ldw = 256; n0s = tn * 32; k0 = tk * 32; WT = WgT; ldwt = 512; n0d = n0s;
    } else {                   // Wo 256x768 -> WoT 768x256
        const int id4 = id - 448, tn = id4 >> 3, tk = id4 & 7;
        W = Wo; ldw = 768; n0s = tn * 32; k0 = tk * 32; WT = WoT; ldwt = 256; n0d = n0s;
    }
#pragma unroll
    for (int p = 0; p < 4; ++p) {
        const int rr = r0 + p * 8;
        Ts[rr][cc] = W[(size_t)(k0 + rr) * ldw + n0s + cc];
    }
    __syncthreads();
#pragma unroll
    for (int p = 0; p < 4; ++p) {
        const int rr = r0 + p * 8;
        WT[(size_t)(n0d + rr) * ldwt + k0 + cc] = f2bf(Ts[cc][rr]);
    }
}

// ---------------- MFMA GEMM mainloop ----------------
// block tile 64 x (NT*32), 4 waves as 2(m) x 2(n), wave tile 32 x (NT*16).
// A: M x K row-major bf16.  BT: N x K row-major bf16 (i.e. B transposed).
// LDS rows padded to 40 shorts (80 B) -> 16B-aligned b128, 2-way-max bank alias.
template<int NT>
__device__ inline void gemm_tiles(const short* __restrict__ A, const short* __restrict__ BT,
                                  int K, int row0, int col0,
                                  short* As, short* Bs, f32x4 acc[2][NT]) {
    const int t = threadIdx.x;
    const int lane = t & 63, wid = t >> 6;
    const int wm = wid & 1, wn = wid >> 1;
    const int quad = lane >> 4, lm = lane & 15;
#pragma unroll
    for (int mt = 0; mt < 2; ++mt)
#pragma unroll
        for (int nt = 0; nt < NT; ++nt) {
            f32x4 z = {0.f, 0.f, 0.f, 0.f};
            acc[mt][nt] = z;
        }
    for (int k0 = 0; k0 < K; k0 += 32) {
        {   // stage A: 64 rows x 32 k
            const int row = t >> 2, cg = t & 3;
            *(bf16x8*)&As[row * 40 + cg * 8] =
                *(const bf16x8*)&A[(size_t)(row0 + row) * K + k0 + cg * 8];
        }
#pragma unroll
        for (int p = 0; p < NT / 2; ++p) {  // stage BT: NT*32 cols x 32 k
            const int idx = t + p * 256;
            const int col = idx >> 2, cg = idx & 3;
            *(bf16x8*)&Bs[col * 40 + cg * 8] =
                *(const bf16x8*)&BT[(size_t)(col0 + col) * K + k0 + cg * 8];
        }
        __syncthreads();
        bf16x8 af[2], bfr[NT];
#pragma unroll
        for (int mt = 0; mt < 2; ++mt)
            af[mt] = *(bf16x8*)&As[(wm * 32 + mt * 16 + lm) * 40 + quad * 8];
#pragma unroll
        for (int nt = 0; nt < NT; ++nt)
            bfr[nt] = *(bf16x8*)&Bs[(wn * NT * 16 + nt * 16 + lm) * 40 + quad * 8];
#pragma unroll
        for (int mt = 0; mt < 2; ++mt)
#pragma unroll
            for (int nt = 0; nt < NT; ++nt)
                acc[mt][nt] = __builtin_amdgcn_mfma_f32_16x16x32_bf16(
                    af[mt], bfr[nt], acc[mt][nt], 0, 0, 0);
        __syncthreads();
    }
}

// ---------------- GEMM 1: qkv (4096x256 @ 256x768) ----------------
__global__ __launch_bounds__(256) void gemm_qkv(
    const short* __restrict__ A, const short* __restrict__ BT,
    const float* __restrict__ bq, const float* __restrict__ bk, const float* __restrict__ bv,
    float* __restrict__ Q, float* __restrict__ Kk, float* __restrict__ V) {
    __shared__ short As[64 * 40];
    __shared__ short Bs[128 * 40];
    f32x4 acc[2][4];
    const int row0 = blockIdx.x * 64, col0 = blockIdx.y * 128;
    gemm_tiles<4>(A, BT, 256, row0, col0, As, Bs, acc);
    const int lane = threadIdx.x & 63, wid = threadIdx.x >> 6;
    const int wm = wid & 1, wn = wid >> 1, quad = lane >> 4, lm = lane & 15;
    const int chunk = col0 >> 8;
    float* dst = chunk == 0 ? Q : (chunk == 1 ? Kk : V);
    const float* bias = chunk == 0 ? bq : (chunk == 1 ? bk : bv);
#pragma unroll
    for (int mt = 0; mt < 2; ++mt)
#pragma unroll
        for (int nt = 0; nt < 4; ++nt) {
            const int col = col0 + wn * 64 + nt * 16 + lm;
            const int cm = col & 255;
            const float bb = bias[cm];
#pragma unroll
            for (int r = 0; r < 4; ++r) {
                const int row = row0 + wm * 32 + mt * 16 + quad * 4 + r;
                dst[(size_t)row * 256 + cm] = acc[mt][nt][r] + bb;
            }
        }
}

// ---------------- GEMM 2: vec_proj (12288x256 @ 256x512) ----------------
__global__ __launch_bounds__(256) void gemm_vec(
    const short* __restrict__ A, const short* __restrict__ BT, float* __restrict__ C) {
    __shared__ short As[64 * 40];
    __shared__ short Bs[128 * 40];
    f32x4 acc[2][4];
    const int row0 = blockIdx.x * 64, col0 = blockIdx.y * 128;
    gemm_tiles<4>(A, BT, 256, row0, col0, As, Bs, acc);
    const int lane = threadIdx.x & 63, wid = threadIdx.x >> 6;
    const int wm = wid & 1, wn = wid >> 1, quad = lane >> 4, lm = lane & 15;
#pragma unroll
    for (int mt = 0; mt < 2; ++mt)
#pragma unroll
        for (int nt = 0; nt < 4; ++nt) {
            const int col = col0 + wn * 64 + nt * 16 + lm;
#pragma unroll
            for (int r = 0; r < 4; ++r) {
                const int row = row0 + wm * 32 + mt * 16 + quad * 4 + r;
                C[(size_t)row * 512 + col] = acc[mt][nt][r];
            }
        }
}

// ---------------- GEMM 3: gate (4096x512 @ 512x256), NT=2 ----------------
__global__ __launch_bounds__(256) void gemm_gate(
    const short* __restrict__ A, const short* __restrict__ BT,
    const float* __restrict__ bg, float* __restrict__ gate) {
    __shared__ short As[64 * 40];
    __shared__ short Bs[64 * 40];
    f32x4 acc[2][2];
    const int row0 = blockIdx.x * 64, col0 = blockIdx.y * 64;
    gemm_tiles<2>(A, BT, 512, row0, col0, As, Bs, acc);
    const int lane = threadIdx.x & 63, wid = threadIdx.x >> 6;
    const int wm = wid & 1, wn = wid >> 1, quad = lane >> 4, lm = lane & 15;
#pragma unroll
    for (int mt = 0; mt < 2; ++mt)
#pragma unroll
        for (int nt = 0; nt < 2; ++nt) {
            const int col = col0 + wn * 32 + nt * 16 + lm;
            const float bb = bg[col];
#pragma unroll
            for (int r = 0; r < 4; ++r) {
                const int row = row0 + wm * 32 + mt * 16 + quad * 4 + r;
                const float z = acc[mt][nt][r] + bb;
                gate[(size_t)row * 256 + col] = 1.f / (1.f + __expf(-z));
            }
        }
}

// ---------------- GEMM 4: o = x_out @ Wo + bo (4096x256 @ 256x768) ----------------
__global__ __launch_bounds__(256) void gemm_out(
    const short* __restrict__ A, const short* __restrict__ BT,
    const float* __restrict__ bo, float* __restrict__ O) {
    __shared__ short As[64 * 40];
    __shared__ short Bs[128 * 40];
    f32x4 acc[2][4];
    const int row0 = blockIdx.x * 64, col0 = blockIdx.y * 128;
    gemm_tiles<4>(A, BT, 256, row0, col0, As, Bs, acc);
    const int lane = threadIdx.x & 63, wid = threadIdx.x >> 6;
    const int wm = wid & 1, wn = wid >> 1, quad = lane >> 4, lm = lane & 15;
#pragma unroll
    for (int mt = 0; mt < 2; ++mt)
#pragma unroll
        for (int nt = 0; nt < 4; ++nt) {
            const int col = col0 + wn * 64 + nt * 16 + lm;
            const float bb = bo[col];
#pragma unroll
            for (int r = 0; r < 4; ++r) {
                const int row = row0 + wm * 32 + mt * 16 + quad * 4 + r;
                O[(size_t)row * 768 + col] = acc[mt][nt][r] + bb;
            }
        }
}

// ---------------- vec post: vec_dot, vec_norm, invariants (bf16) ----------------
__global__ __launch_bounds__(256) void vecpost_kernel(
    const float* __restrict__ x, const float* __restrict__ vec_proj,
    const float* __restrict__ alpha_dot, const float* __restrict__ alpha_norm,
    float* __restrict__ vec_dot, float* __restrict__ vec_norm, short* __restrict__ inv_bf) {
    const int row0 = blockIdx.x * 16;
    const int ch = threadIdx.x;
    const float ad = alpha_dot[0], an = alpha_norm[0];
#pragma unroll
    for (int r = 0; r < 16; ++r) {
        const int row = row0 + r;
        float dot = 0.f;
#pragma unroll
        for (int c = 0; c < 3; ++c) {
            const float a1 = vec_proj[(size_t)(row * 3 + c) * 512 + ch];
            const float a2 = vec_proj[(size_t)(row * 3 + c) * 512 + 256 + ch];
            dot = fmaf(a1, a2, dot);
        }
        const float v0 = x[(size_t)row * 1024 + 256 + ch];
        const float v1 = x[(size_t)row * 1024 + 512 + ch];
        const float v2 = x[(size_t)row * 1024 + 768 + ch];
        const float nrm = sqrtf(v0 * v0 + v1 * v1 + v2 * v2);
        vec_dot[(size_t)row * 256 + ch] = dot;
        vec_norm[(size_t)row * 256 + ch] = nrm;
        inv_bf[(size_t)row * 512 + ch] = f2bf(ad * dot);
        inv_bf[(size_t)row * 512 + 256 + ch] = f2bf(an * nrm);
    }
}

// ---------------- attention scores + softmax (unchanged from R1) ----------------
__global__ __launch_bounds__(256) void attn_score_kernel(
    const float* __restrict__ Q, const float* __restrict__ K,
    float* __restrict__ attnw) {
    const int bh = blockIdx.x >> 6;
    const int tile = blockIdx.x & 63;
    const int b = bh >> 3, hd = bh & 7;
    const int i0 = tile * 32;
    const int t = threadIdx.x;

    __shared__ float Qs[32][36];
    __shared__ float Ks[96][36];

    {
        const int row = t >> 3, c4 = t & 7;
        const float4 qv = *(const float4*)&Q[((size_t)(b * Nn + i0 + row)) * Hh + hd * Dd + 4 * c4];
        *(float4*)&Qs[row][4 * c4] = qv;
    }
#pragma unroll
    for (int kk = 0; kk < 3; ++kk) {
        const int idx = t + kk * 256;
        const int row = idx >> 3, c4 = idx & 7;
        const int j = i0 - WIN + row;
        float4 kv = make_float4(0.f, 0.f, 0.f, 0.f);
        if (j >= 0 && j < Nn)
            kv = *(const float4*)&K[((size_t)(b * Nn + j)) * Hh + hd * Dd + 4 * c4];
        *(float4*)&Ks[row][4 * c4] = kv;
    }
    __syncthreads();

    const int i = t >> 3, sub = t & 7;
    float4 qr[8];
#pragma unroll
    for (int c = 0; c < 8; ++c) qr[c] = *(const float4*)&Qs[i][4 * c];

    float s[9];
#pragma unroll
    for (int k = 0; k < 9; ++k) {
        const int w = sub + 8 * k;
        if (w <= 64) {
            const int row = i + w;
            float dot = 0.f;
#pragma unroll
            for (int c = 0; c < 8; ++c) {
                const float4 kv = *(const float4*)&Ks[row][4 * c];
                dot = fmaf(qr[c].x, kv.x, dot);
                dot = fmaf(qr[c].y, kv.y, dot);
                dot = fmaf(qr[c].z, kv.z, dot);
                dot = fmaf(qr[c].w, kv.w, dot);
            }
            s[k] = dot * 0.17677669529663687f;
        } else {
            s[k] = -1e30f;
        }
    }
    float m = s[0];
#pragma unroll
    for (int k = 1; k < 9; ++k) m = fmaxf(m, s[k]);
#pragma unroll
    for (int off = 1; off < 8; off <<= 1) m = fmaxf(m, __shfl_xor(m, off, 64));
    float sum = 0.f;
#pragma unroll
    for (int k = 0; k < 9; ++k) {
        const float e = (sub + 8 * k <= 64) ? __expf(s[k] - m) : 0.f;
        s[k] = e;
        sum += e;
    }
#pragma unroll
    for (int off = 1; off < 8; off <<= 1) sum += __shfl_xor(sum, off, 64);
    const float inv = 1.f / sum;
    float* dst = &attnw[((size_t)bh * Nn + (i0 + i)) * WL];
#pragma unroll
    for (int k = 0; k < 9; ++k) {
        const int w = sub + 8 * k;
        if (w <= 64) dst[w] = s[k] * inv;
    }
}

// ---------------- attention aggregation (+ bf16 x_out for gemm_out) ----------------
__global__ __launch_bounds__(256) void attn_agg_kernel(
    const float* __restrict__ x, const float* __restrict__ V,
    const float* __restrict__ attnw,
    float* __restrict__ vec_aggr, short* __restrict__ xout_bf) {
    const int bh = blockIdx.x >> 6;
    const int tile = blockIdx.x & 63;
    const int b = bh >> 3, hd = bh & 7;
    const int i0 = tile * 32;
    const int t = threadIdx.x;

    __shared__ float Ss[96][132];
    __shared__ float Pl[32][72];

#pragma unroll
    for (int kk = 0; kk < 12; ++kk) {
        const int idx = t + kk * 256;
        const int row = idx >> 5, c4 = idx & 31;
        const int j = i0 - WIN + row;
        float4 val = make_float4(0.f, 0.f, 0.f, 0.f);
        if (j >= 0 && j < Nn) {
            if (c4 < 8) {
                val = *(const float4*)&V[((size_t)(b * Nn + j)) * Hh + hd * Dd + 4 * c4];
            } else {
                const int cc = (c4 - 8) >> 3, s4 = c4 & 7;
                val = *(const float4*)&x[((size_t)(b * Nn + j)) * 1024 + (1 + cc) * Hh + hd * Dd + 4 * s4];
            }
        }
        *(float4*)&Ss[row][4 * c4] = val;
    }
    {
        const int i = t >> 3, sub = t & 7;
        const float* src = &attnw[((size_t)bh * Nn + (i0 + i)) * WL];
#pragma unroll
        for (int k = 0; k < 9; ++k) {
            const int w = sub + 8 * k;
            if (w <= 64) Pl[i][w + 3] = src[w];
        }
        if (sub == 0) {
            Pl[i][0] = 0.f; Pl[i][1] = 0.f; Pl[i][2] = 0.f;
            Pl[i][68] = 0.f; Pl[i][69] = 0.f; Pl[i][70] = 0.f; Pl[i][71] = 0.f;
        }
    }
    __syncthreads();

    const int c4 = t & 31, itile = t >> 5;
    float4 acc[4];
#pragma unroll
    for (int ii = 0; ii < 4; ++ii) acc[ii] = make_float4(0.f, 0.f, 0.f, 0.f);
#pragma unroll 4
    for (int jj = 0; jj < 68; ++jj) {
        const int row = itile * 4 + jj;
        const float4 sv = *(const float4*)&Ss[row][4 * c4];
#pragma unroll
        for (int ii = 0; ii < 4; ++ii) {
            const float p = Pl[itile * 4 + ii][jj - ii + 3];
            acc[ii].x = fmaf(p, sv.x, acc[ii].x);
            acc[ii].y = fmaf(p, sv.y, acc[ii].y);
            acc[ii].z = fmaf(p, sv.z, acc[ii].z);
            acc[ii].w = fmaf(p, sv.w, acc[ii].w);
        }
    }
#pragma unroll
    for (int ii = 0; ii < 4; ++ii) {
        const int i = i0 + itile * 4 + ii;
        if (c4 < 8) {
            // x_out in (b,n,ch) layout, bf16, for gemm_out's A operand
            short* xb = &xout_bf[((size_t)(b * Nn + i)) * 256 + hd * Dd + 4 * c4];
            xb[0] = f2bf(acc[ii].x); xb[1] = f2bf(acc[ii].y);
            xb[2] = f2bf(acc[ii].z); xb[3] = f2bf(acc[ii].w);
        } else {
            const int cc = (c4 - 8) >> 3, s4 = c4 & 7;
            *(float4*)&vec_aggr[(((size_t)bh * Nn + i) * 3 + cc) * Dd + 4 * s4] = acc[ii];
        }
    }
}

// ---------------- final combine ----------------
__global__ __launch_bounds__(256) void final_kernel(
    const float* __restrict__ x, const float* __restrict__ O,
    const float* __restrict__ vec_dot, const float* __restrict__ vec_norm,
    const float* __restrict__ gate, const float* __restrict__ vec_aggr,
    float* __restrict__ out) {
    const int row0 = blockIdx.x * 8;
    const int ch = threadIdx.x;
    const int hd = ch >> 5, dd = ch & 31;
#pragma unroll
    for (int r = 0; r < 8; ++r) {
        const int row = row0 + r;
        const int b = row >> 11, n = row & (Nn - 1);
        const float o1 = O[(size_t)row * 768 + ch];
        const float o2 = O[(size_t)row * 768 + 256 + ch];
        const float o3 = O[(size_t)row * 768 + 512 + ch];
        const float vd = vec_dot[(size_t)row * 256 + ch];
        const float vn = vec_norm[(size_t)row * 256 + ch];
        out[(size_t)row * 1024 + ch] = vd * o1 + vn * o2 + o3;
        const float g = gate[(size_t)row * 256 + ch];
        const size_t vabase = (((size_t)(b * NH + hd)) * Nn + n) * 96 + dd;
#pragma unroll
        for (int c = 0; c < 3; ++c) {
            const float va = vec_aggr[vabase + c * Dd];
            const float vv = x[(size_t)row * 1024 + (1 + c) * Hh + ch];
            out[(size_t)row * 1024 + (1 + c) * Hh + ch] = g * va + vv;
        }
    }
}

extern "C" void kernel_launch(void* const* d_in, const int* in_sizes, int n_in,
                              void* d_out, int out_size, void* d_ws, size_t ws_size,
                              hipStream_t stream) {
    const float* x  = (const float*)d_in[0];
    const float* Wq = (const float*)d_in[1];
    const float* bq = (const float*)d_in[2];
    const float* Wk = (const float*)d_in[3];
    const float* bk = (const float*)d_in[4];
    const float* Wv = (const float*)d_in[5];
    const float* bv = (const float*)d_in[6];
    const float* Wo = (const float*)d_in[7];
    const float* bo = (const float*)d_in[8];
    const float* Wvec = (const float*)d_in[9];
    const float* alpha_dot  = (const float*)d_in[10];
    const float* alpha_norm = (const float*)d_in[11];
    const float* Wg = (const float*)d_in[12];
    const float* bg = (const float*)d_in[13];

    float* ws = (float*)d_ws;
    float* Q        = ws;              // 1048576
    float* Kk       = ws + 1048576;    // 1048576
    float* V        = ws + 2097152;    // 1048576
    float* vec_dot  = ws + 3145728;    // 1048576
    float* vec_norm = ws + 4194304;    // 1048576
    float* gate     = ws + 5242880;    // 1048576
    float* vec_aggr = ws + 6291456;    // 3145728
    float* vec_proj = ws + 9437184;    // 6291456 (12288x512)
    float* O        = vec_proj;        // aliased: vec_proj dead before O written (3145728)

    short* sbase   = (short*)(ws + 15728640);
    short* xs_bf   = sbase;            // 1048576
    short* vec_bf  = sbase + 1048576;  // 3145728
    short* inv_bf  = sbase + 4194304;  // 2097152
    short* xout_bf = sbase + 6291456;  // 1048576
    short* WqkvT   = sbase + 7340032;  // 196608 (768x256)
    short* WvecT   = sbase + 7536640;  // 131072 (512x256)
    short* WgT     = sbase + 7667712;  // 131072 (256x512)
    short* WoT     = sbase + 7798784;  // 196608 (768x256)

    float* out = (float*)d_out;
    float* attnw = out + (size_t)Bc * Nn * 4 * Hh;  // 4,194,304

    castx_kernel<<<2048, 256, 0, stream>>>(x, xs_bf, vec_bf);
    castw_kernel<<<640, 256, 0, stream>>>(Wq, Wk, Wv, Wvec, Wg, Wo,
                                          WqkvT, WvecT, WgT, WoT);
    gemm_qkv<<<dim3(64, 6), 256, 0, stream>>>(xs_bf, WqkvT, bq, bk, bv, Q, Kk, V);
    gemm_vec<<<dim3(192, 4), 256, 0, stream>>>(vec_bf, WvecT, vec_proj);
    vecpost_kernel<<<256, 256, 0, stream>>>(x, vec_proj, alpha_dot, alpha_norm,
                                            vec_dot, vec_norm, inv_bf);
    gemm_gate<<<dim3(64, 4), 256, 0, stream>>>(inv_bf, WgT, bg, gate);
    attn_score_kernel<<<1024, 256, 0, stream>>>(Q, Kk, attnw);
    attn_agg_kernel<<<1024, 256, 0, stream>>>(x, V, attnw, vec_aggr, xout_bf);
    gemm_out<<<dim3(64, 6), 256, 0, stream>>>(xout_bf, WoT, bo, O);
    final_kernel<<<512, 256, 0, stream>>>(x, O, vec_dot, vec_norm, gate,
                                          vec_aggr, out);
}

// Round 4
// 152.829 us; speedup vs baseline: 5.3975x; 1.2202x over previous
//
#include <hip/hip_runtime.h>
#include <math.h>

#define Bc 2
#define Nn 2048
#define Hh 256
#define NH 8
#define Dd 32
#define WIN 32
#define WL 65
#define BN (Bc * Nn)   // 4096

typedef __attribute__((ext_vector_type(8))) short bf16x8;
typedef __attribute__((ext_vector_type(4))) float f32x4;

__device__ inline short f2bf(float f) {
    union { float f; unsigned u; } v; v.f = f;
    unsigned r = v.u + 0x7fffu + ((v.u >> 16) & 1u);
    return (short)(r >> 16);
}

// ---------------- castx: bf16 copies + vec_norm + norm-half of invariants ----------
// one thread per (bn, ch); grid 4096 x 256
__global__ __launch_bounds__(256) void castx_kernel(
    const float* __restrict__ x, const float* __restrict__ alpha_norm,
    short* __restrict__ xs_bf, short* __restrict__ vec_bf,
    float* __restrict__ vec_norm, short* __restrict__ inv_bf) {
    const int idx = blockIdx.x * 256 + threadIdx.x;
    const int bn = idx >> 8, ch = idx & 255;
    const size_t base = (size_t)bn * 1024 + ch;
    const float xs = x[base];
    const float v0 = x[base + 256], v1 = x[base + 512], v2 = x[base + 768];
    xs_bf[(size_t)bn * 256 + ch] = f2bf(xs);
    vec_bf[((size_t)0 * BN + bn) * 256 + ch] = f2bf(v0);
    vec_bf[((size_t)1 * BN + bn) * 256 + ch] = f2bf(v1);
    vec_bf[((size_t)2 * BN + bn) * 256 + ch] = f2bf(v2);
    const float nrm = sqrtf(v0 * v0 + v1 * v1 + v2 * v2);
    vec_norm[(size_t)bn * 256 + ch] = nrm;
    inv_bf[(size_t)bn * 512 + 256 + ch] = f2bf(alpha_norm[0] * nrm);
}

// ---------------- cast + transpose weights -> bf16 B^T (N x K) ----------------
__global__ __launch_bounds__(256) void castw_kernel(
    const float* __restrict__ Wq, const float* __restrict__ Wk, const float* __restrict__ Wv,
    const float* __restrict__ Wvec, const float* __restrict__ Wg, const float* __restrict__ Wo,
    short* __restrict__ WqkvT, short* __restrict__ WvecT,
    short* __restrict__ WgT, short* __restrict__ WoT) {
    __shared__ float Ts[32][33];
    const int t = threadIdx.x;
    const int cc = t & 31, r0 = t >> 5;
    const int id = blockIdx.x;
    const float* W; int ldw; short* WT; int ldwt; int n0s, k0, n0d;
    if (id < 192) {            // [Wq|Wk|Wv] 256x768 -> WqkvT 768x256
        const int tn = id >> 3, tk = id & 7, sel = tn >> 3;
        W = sel == 0 ? Wq : (sel == 1 ? Wk : Wv); ldw = 256;
        n0s = (tn & 7) * 32; k0 = tk * 32; WT = WqkvT; ldwt = 256; n0d = tn * 32;
    } else if (id < 320) {     // Wvec 256x512 -> WvecT 512x256
        const int id2 = id - 192, tn = id2 >> 3, tk = id2 & 7;
        W = Wvec; ldw = 512; n0s = tn * 32; k0 = tk * 32; WT = WvecT; ldwt = 256; n0d = n0s;
    } else if (id < 448) {     // Wg 512x256 -> WgT 256x512
        const int id3 = id - 320, tn = id3 >> 4, tk = id3 & 15;
        W = Wg; ldw = 256; n0s = tn * 32; k0 = tk * 32; WT = WgT; ldwt = 512; n0d = n0s;
    } else {                   // Wo 256x768 -> WoT 768x256
        const int id4 = id - 448, tn = id4 >> 3, tk = id4 & 7;
        W = Wo; ldw = 768; n0s = tn * 32; k0 = tk * 32; WT = WoT; ldwt = 256; n0d = n0s;
    }
#pragma unroll
    for (int p = 0; p < 4; ++p) {
        const int rr = r0 + p * 8;
        Ts[rr][cc] = W[(size_t)(k0 + rr) * ldw + n0s + cc];
    }
    __syncthreads();
#pragma unroll
    for (int p = 0; p < 4; ++p) {
        const int rr = r0 + p * 8;
        WT[(size_t)(n0d + rr) * ldwt + k0 + cc] = f2bf(Ts[cc][rr]);
    }
}

// ---------------- shared MFMA mainloop (64 x NT*32 block tile) ----------------
template<int NT>
__device__ inline void gemm_tiles(const short* __restrict__ A, const short* __restrict__ BT,
                                  int K, int row0, int col0,
                                  short* As, short* Bs, f32x4 acc[2][NT]) {
    const int t = threadIdx.x;
    const int lane = t & 63, wid = t >> 6;
    const int wm = wid & 1, wn = wid >> 1;
    const int quad = lane >> 4, lm = lane & 15;
#pragma unroll
    for (int mt = 0; mt < 2; ++mt)
#pragma unroll
        for (int nt = 0; nt < NT; ++nt) {
            f32x4 z = {0.f, 0.f, 0.f, 0.f};
            acc[mt][nt] = z;
        }
    for (int k0 = 0; k0 < K; k0 += 32) {
        {
            const int row = t >> 2, cg = t & 3;
            *(bf16x8*)&As[row * 40 + cg * 8] =
                *(const bf16x8*)&A[(size_t)(row0 + row) * K + k0 + cg * 8];
        }
#pragma unroll
        for (int p = 0; p < NT / 2; ++p) {
            const int idx = t + p * 256;
            const int col = idx >> 2, cg = idx & 3;
            *(bf16x8*)&Bs[col * 40 + cg * 8] =
                *(const bf16x8*)&BT[(size_t)(col0 + col) * K + k0 + cg * 8];
        }
        __syncthreads();
        bf16x8 af[2], bfr[NT];
#pragma unroll
        for (int mt = 0; mt < 2; ++mt)
            af[mt] = *(bf16x8*)&As[(wm * 32 + mt * 16 + lm) * 40 + quad * 8];
#pragma unroll
        for (int nt = 0; nt < NT; ++nt)
            bfr[nt] = *(bf16x8*)&Bs[(wn * NT * 16 + nt * 16 + lm) * 40 + quad * 8];
#pragma unroll
        for (int mt = 0; mt < 2; ++mt)
#pragma unroll
            for (int nt = 0; nt < NT; ++nt)
                acc[mt][nt] = __builtin_amdgcn_mfma_f32_16x16x32_bf16(
                    af[mt], bfr[nt], acc[mt][nt], 0, 0, 0);
        __syncthreads();
    }
}

// ---------------- GEMM 1: qkv -> bf16 Q,K,V ----------------
__global__ __launch_bounds__(256) void gemm_qkv(
    const short* __restrict__ A, const short* __restrict__ BT,
    const float* __restrict__ bq, const float* __restrict__ bk, const float* __restrict__ bv,
    short* __restrict__ Qb, short* __restrict__ Kb, short* __restrict__ Vb) {
    __shared__ short As[64 * 40];
    __shared__ short Bs[128 * 40];
    f32x4 acc[2][4];
    const int row0 = blockIdx.x * 64, col0 = blockIdx.y * 128;
    gemm_tiles<4>(A, BT, 256, row0, col0, As, Bs, acc);
    const int lane = threadIdx.x & 63, wid = threadIdx.x >> 6;
    const int wm = wid & 1, wn = wid >> 1, quad = lane >> 4, lm = lane & 15;
    const int chunk = col0 >> 8;
    short* dst = chunk == 0 ? Qb : (chunk == 1 ? Kb : Vb);
    const float* bias = chunk == 0 ? bq : (chunk == 1 ? bk : bv);
#pragma unroll
    for (int mt = 0; mt < 2; ++mt)
#pragma unroll
        for (int nt = 0; nt < 4; ++nt) {
            const int col = col0 + wn * 64 + nt * 16 + lm;
            const int cm = col & 255;
            const float bb = bias[cm];
#pragma unroll
            for (int r = 0; r < 4; ++r) {
                const int row = row0 + wm * 32 + mt * 16 + quad * 4 + r;
                dst[(size_t)row * 256 + cm] = f2bf(acc[mt][nt][r] + bb);
            }
        }
}

// ---------------- GEMM 2: vec_proj + fused vec_dot ----------------
// block 64 bn-rows x 64 ch-cols; A = 3 planes of vec_bf; B = 2 column halves.
__global__ __launch_bounds__(256) void gemm_vecdot(
    const short* __restrict__ A, const short* __restrict__ BT,
    const float* __restrict__ alpha_dot,
    float* __restrict__ vec_dot, short* __restrict__ inv_bf) {
    __shared__ short As[3][64 * 40];
    __shared__ short Bs[2][64 * 40];
    const int row0 = blockIdx.x * 64, ch0 = blockIdx.y * 64;
    const int t = threadIdx.x, lane = t & 63, wid = t >> 6;
    const int wm = wid & 1, wn = wid >> 1, quad = lane >> 4, lm = lane & 15;
    f32x4 acc[3][2][2][2];  // [plane][half][mt][nt]
#pragma unroll
    for (int p = 0; p < 3; ++p)
#pragma unroll
        for (int h = 0; h < 2; ++h)
#pragma unroll
            for (int mt = 0; mt < 2; ++mt)
#pragma unroll
                for (int nt = 0; nt < 2; ++nt) {
                    f32x4 z = {0.f, 0.f, 0.f, 0.f};
                    acc[p][h][mt][nt] = z;
                }
    for (int k0 = 0; k0 < 256; k0 += 32) {
        const int row = t >> 2, cg = t & 3;
#pragma unroll
        for (int p = 0; p < 3; ++p)
            *(bf16x8*)&As[p][row * 40 + cg * 8] =
                *(const bf16x8*)&A[((size_t)p * BN + row0 + row) * 256 + k0 + cg * 8];
#pragma unroll
        for (int h = 0; h < 2; ++h)
            *(bf16x8*)&Bs[h][row * 40 + cg * 8] =
                *(const bf16x8*)&BT[(size_t)(h * 256 + ch0 + row) * 256 + k0 + cg * 8];
        __syncthreads();
        bf16x8 af[3][2], bfr[2][2];
#pragma unroll
        for (int p = 0; p < 3; ++p)
#pragma unroll
            for (int mt = 0; mt < 2; ++mt)
                af[p][mt] = *(bf16x8*)&As[p][(wm * 32 + mt * 16 + lm) * 40 + quad * 8];
#pragma unroll
        for (int h = 0; h < 2; ++h)
#pragma unroll
            for (int nt = 0; nt < 2; ++nt)
                bfr[h][nt] = *(bf16x8*)&Bs[h][(wn * 32 + nt * 16 + lm) * 40 + quad * 8];
#pragma unroll
        for (int p = 0; p < 3; ++p)
#pragma unroll
            for (int h = 0; h < 2; ++h)
#pragma unroll
                for (int mt = 0; mt < 2; ++mt)
#pragma unroll
                    for (int nt = 0; nt < 2; ++nt)
                        acc[p][h][mt][nt] = __builtin_amdgcn_mfma_f32_16x16x32_bf16(
                            af[p][mt], bfr[h][nt], acc[p][h][mt][nt], 0, 0, 0);
        __syncthreads();
    }
    const float ad = alpha_dot[0];
#pragma unroll
    for (int mt = 0; mt < 2; ++mt)
#pragma unroll
        for (int nt = 0; nt < 2; ++nt) {
            const int col = ch0 + wn * 32 + nt * 16 + lm;
#pragma unroll
            for (int r = 0; r < 4; ++r) {
                const int row = row0 + wm * 32 + mt * 16 + quad * 4 + r;
                float dot = 0.f;
#pragma unroll
                for (int p = 0; p < 3; ++p)
                    dot = fmaf(acc[p][0][mt][nt][r], acc[p][1][mt][nt][r], dot);
                vec_dot[(size_t)row * 256 + col] = dot;
                inv_bf[(size_t)row * 512 + col] = f2bf(ad * dot);
            }
        }
}

// ---------------- GEMM 3: gate ----------------
__global__ __launch_bounds__(256) void gemm_gate(
    const short* __restrict__ A, const short* __restrict__ BT,
    const float* __restrict__ bg, float* __restrict__ gate) {
    __shared__ short As[64 * 40];
    __shared__ short Bs[64 * 40];
    f32x4 acc[2][2];
    const int row0 = blockIdx.x * 64, col0 = blockIdx.y * 64;
    gemm_tiles<2>(A, BT, 512, row0, col0, As, Bs, acc);
    const int lane = threadIdx.x & 63, wid = threadIdx.x >> 6;
    const int wm = wid & 1, wn = wid >> 1, quad = lane >> 4, lm = lane & 15;
#pragma unroll
    for (int mt = 0; mt < 2; ++mt)
#pragma unroll
        for (int nt = 0; nt < 2; ++nt) {
            const int col = col0 + wn * 32 + nt * 16 + lm;
            const float bb = bg[col];
#pragma unroll
            for (int r = 0; r < 4; ++r) {
                const int row = row0 + wm * 32 + mt * 16 + quad * 4 + r;
                const float z = acc[mt][nt][r] + bb;
                gate[(size_t)row * 256 + col] = 1.f / (1.f + __expf(-z));
            }
        }
}

// ---------------- fused attention: scores(MFMA) + softmax + PV(MFMA) + gate ------
// one block per (bh, 32-i tile); 1024 blocks x 256 thr.
__global__ __launch_bounds__(256) void attn_fused(
    const short* __restrict__ Qb, const short* __restrict__ Kb,
    const short* __restrict__ Vb, const short* __restrict__ vec_bf,
    const float* __restrict__ gate, const float* __restrict__ x,
    float* __restrict__ attnw, float* __restrict__ out, short* __restrict__ xout_bf) {
    const int bh = blockIdx.x >> 6, tile = blockIdx.x & 63;
    const int b = bh >> 3, hd = bh & 7;
    const int i0 = tile * 32;
    const int t = threadIdx.x, lane = t & 63, wid = t >> 6;
    const int wm = wid & 1, wn = wid >> 1, quad = lane >> 4, lm = lane & 15;

    __shared__ __align__(16) short Qs[32 * 40];    // i, d
    __shared__ __align__(16) short Ks[96 * 40];    // j, d  (OOB rows = 0)
    __shared__ __align__(16) float Sc[32 * 100];   // i, j raw dots
    __shared__ __align__(16) short Pb[32 * 104];   // i, j bf16 weights (band, else 0)
    __shared__ __align__(16) short St[128 * 112];  // dim, j  (S transposed)

    // zero Pb (band matrix needs zero fill)
    for (int idx = t; idx < 32 * 104 / 2; idx += 256) ((int*)Pb)[idx] = 0;
    // stage Q (32 x 32 bf16)
    if (t < 128) {
        const int row = t >> 2, cg = t & 3;
        *(bf16x8*)&Qs[row * 40 + cg * 8] =
            *(const bf16x8*)&Qb[((size_t)(b * Nn + i0 + row)) * 256 + hd * 32 + cg * 8];
    }
    // stage K (96 x 32 bf16, halo, OOB -> 0)
#pragma unroll
    for (int kk = 0; kk < 2; ++kk) {
        const int idx = t + kk * 256;
        if (idx < 384) {
            const int row = idx >> 2, cg = idx & 3;
            const int j = i0 - WIN + row;
            bf16x8 kv = {0, 0, 0, 0, 0, 0, 0, 0};
            if (j >= 0 && j < Nn)
                kv = *(const bf16x8*)&Kb[((size_t)(b * Nn + j)) * 256 + hd * 32 + cg * 8];
            *(bf16x8*)&Ks[row * 40 + cg * 8] = kv;
        }
    }
    // stage S^T (128 dims x 96 j): V dims 0-31, vec dims 32-127
    {
        const int chunk = t >> 4, j0 = t & 15;
#pragma unroll
        for (int it = 0; it < 6; ++it) {
            const int jr = j0 + it * 16;
            const int j = i0 - WIN + jr;
            bf16x8 val = {0, 0, 0, 0, 0, 0, 0, 0};
            if (j >= 0 && j < Nn) {
                if (chunk < 4)
                    val = *(const bf16x8*)&Vb[((size_t)(b * Nn + j)) * 256 + hd * 32 + chunk * 8];
                else {
                    const int vc = (chunk - 4) >> 2, d0 = ((chunk - 4) & 3) * 8;
                    val = *(const bf16x8*)&vec_bf[((size_t)vc * BN + b * Nn + j) * 256 + hd * 32 + d0];
                }
            }
#pragma unroll
            for (int u = 0; u < 8; ++u) St[(chunk * 8 + u) * 112 + jr] = val[u];
        }
    }
    __syncthreads();

    // scores: 32i x 96j = 2 m-tiles x 6 n-tiles, 3 MFMA per wave
    {
        const bf16x8 aq = *(bf16x8*)&Qs[(wm * 16 + lm) * 40 + quad * 8];
#pragma unroll
        for (int nt = 0; nt < 3; ++nt) {
            const bf16x8 bk = *(bf16x8*)&Ks[((wn * 3 + nt) * 16 + lm) * 40 + quad * 8];
            f32x4 c = {0.f, 0.f, 0.f, 0.f};
            c = __builtin_amdgcn_mfma_f32_16x16x32_bf16(aq, bk, c, 0, 0, 0);
#pragma unroll
            for (int r = 0; r < 4; ++r)
                Sc[(wm * 16 + quad * 4 + r) * 100 + (wn * 3 + nt) * 16 + lm] = c[r];
        }
    }
    __syncthreads();

    // softmax: 8 lanes per i
    {
        const int i = t >> 3, sub = t & 7;
        float s[9];
#pragma unroll
        for (int k = 0; k < 9; ++k) {
            const int w = sub + 8 * k;
            s[k] = (w <= 64) ? Sc[i * 100 + i + w] * 0.17677669529663687f : -1e30f;
        }
        float m = s[0];
#pragma unroll
        for (int k = 1; k < 9; ++k) m = fmaxf(m, s[k]);
#pragma unroll
        for (int off = 1; off < 8; off <<= 1) m = fmaxf(m, __shfl_xor(m, off, 64));
        float sum = 0.f;
#pragma unroll
        for (int k = 0; k < 9; ++k) {
            const float e = (sub + 8 * k <= 64) ? __expf(s[k] - m) : 0.f;
            s[k] = e;
            sum += e;
        }
#pragma unroll
        for (int off = 1; off < 8; off <<= 1) sum += __shfl_xor(sum, off, 64);
        const float inv = 1.f / sum;
        float* dst = &attnw[((size_t)bh * Nn + (i0 + i)) * WL];
#pragma unroll
        for (int k = 0; k < 9; ++k) {
            const int w = sub + 8 * k;
            if (w <= 64) {
                const float pw = s[k] * inv;
                dst[w] = pw;
                Pb[i * 104 + i + w] = f2bf(pw);
            }
        }
    }
    __syncthreads();

    // PV: 32i x 128dim, K=96j: per wave 1 m-tile x 4 n-tiles x 3 k-steps
    f32x4 acc[4];
#pragma unroll
    for (int nt = 0; nt < 4; ++nt) {
        f32x4 z = {0.f, 0.f, 0.f, 0.f};
        acc[nt] = z;
    }
#pragma unroll
    for (int ks = 0; ks < 3; ++ks) {
        const bf16x8 ap = *(bf16x8*)&Pb[(wm * 16 + lm) * 104 + ks * 32 + quad * 8];
#pragma unroll
        for (int nt = 0; nt < 4; ++nt) {
            const bf16x8 bs = *(bf16x8*)&St[(wn * 64 + nt * 16 + lm) * 112 + ks * 32 + quad * 8];
            acc[nt] = __builtin_amdgcn_mfma_f32_16x16x32_bf16(ap, bs, acc[nt], 0, 0, 0);
        }
    }
    // epilogue: dims<32 -> xout_bf; dims>=32 -> gated vec output directly
#pragma unroll
    for (int nt = 0; nt < 4; ++nt) {
        const int dim = wn * 64 + nt * 16 + lm;
#pragma unroll
        for (int r = 0; r < 4; ++r) {
            const int i = wm * 16 + quad * 4 + r;
            const size_t bn = (size_t)(b * Nn + i0 + i);
            if (dim < 32) {
                xout_bf[bn * 256 + hd * 32 + dim] = f2bf(acc[nt][r]);
            } else {
                const int dm = dim - 32, c = dm >> 5, dd = dm & 31;
                const int ch = hd * 32 + dd;
                const float g = gate[bn * 256 + ch];
                const size_t off = bn * 1024 + (1 + c) * 256 + ch;
                out[off] = fmaf(g, acc[nt][r], x[off]);
            }
        }
    }
}

// ---------------- GEMM 4: fused output projection + scalar combine ----------------
// block 64 rows x 64 ch-cols x 3 weight chunks
__global__ __launch_bounds__(256) void gemm_outf(
    const short* __restrict__ A, const short* __restrict__ BT,
    const float* __restrict__ bo,
    const float* __restrict__ vec_dot, const float* __restrict__ vec_norm,
    float* __restrict__ out) {
    __shared__ short As[64 * 40];
    __shared__ short Bs[3][64 * 40];
    const int row0 = blockIdx.x * 64, ch0 = blockIdx.y * 64;
    const int t = threadIdx.x, lane = t & 63, wid = t >> 6;
    const int wm = wid & 1, wn = wid >> 1, quad = lane >> 4, lm = lane & 15;
    f32x4 acc[3][2][2];  // [chunk][mt][nt]
#pragma unroll
    for (int p = 0; p < 3; ++p)
#pragma unroll
        for (int mt = 0; mt < 2; ++mt)
#pragma unroll
            for (int nt = 0; nt < 2; ++nt) {
                f32x4 z = {0.f, 0.f, 0.f, 0.f};
                acc[p][mt][nt] = z;
            }
    for (int k0 = 0; k0 < 256; k0 += 32) {
        const int row = t >> 2, cg = t & 3;
        *(bf16x8*)&As[row * 40 + cg * 8] =
            *(const bf16x8*)&A[(size_t)(row0 + row) * 256 + k0 + cg * 8];
#pragma unroll
        for (int p = 0; p < 3; ++p)
            *(bf16x8*)&Bs[p][row * 40 + cg * 8] =
                *(const bf16x8*)&BT[(size_t)(p * 256 + ch0 + row) * 256 + k0 + cg * 8];
        __syncthreads();
        bf16x8 af[2], bfr[3][2];
#pragma unroll
        for (int mt = 0; mt < 2; ++mt)
            af[mt] = *(bf16x8*)&As[(wm * 32 + mt * 16 + lm) * 40 + quad * 8];
#pragma unroll
        for (int p = 0; p < 3; ++p)
#pragma unroll
            for (int nt = 0; nt < 2; ++nt)
                bfr[p][nt] = *(bf16x8*)&Bs[p][(wn * 32 + nt * 16 + lm) * 40 + quad * 8];
#pragma unroll
        for (int p = 0; p < 3; ++p)
#pragma unroll
            for (int mt = 0; mt < 2; ++mt)
#pragma unroll
                for (int nt = 0; nt < 2; ++nt)
                    acc[p][mt][nt] = __builtin_amdgcn_mfma_f32_16x16x32_bf16(
                        af[mt], bfr[p][nt], acc[p][mt][nt], 0, 0, 0);
        __syncthreads();
    }
#pragma unroll
    for (int mt = 0; mt < 2; ++mt)
#pragma unroll
        for (int nt = 0; nt < 2; ++nt) {
            const int col = ch0 + wn * 32 + nt * 16 + lm;
            const float b1 = bo[col], b2 = bo[256 + col], b3 = bo[512 + col];
#pragma unroll
            for (int r = 0; r < 4; ++r) {
                const int row = row0 + wm * 32 + mt * 16 + quad * 4 + r;
                const float o1 = acc[0][mt][nt][r] + b1;
                const float o2 = acc[1][mt][nt][r] + b2;
                const float o3 = acc[2][mt][nt][r] + b3;
                const float vd = vec_dot[(size_t)row * 256 + col];
                const float vn = vec_norm[(size_t)row * 256 + col];
                out[(size_t)row * 1024 + col] = vd * o1 + vn * o2 + o3;
            }
        }
}

extern "C" void kernel_launch(void* const* d_in, const int* in_sizes, int n_in,
                              void* d_out, int out_size, void* d_ws, size_t ws_size,
                              hipStream_t stream) {
    const float* x  = (const float*)d_in[0];
    const float* Wq = (const float*)d_in[1];
    const float* bq = (const float*)d_in[2];
    const float* Wk = (const float*)d_in[3];
    const float* bk = (const float*)d_in[4];
    const float* Wv = (const float*)d_in[5];
    const float* bv = (const float*)d_in[6];
    const float* Wo = (const float*)d_in[7];
    const float* bo = (const float*)d_in[8];
    const float* Wvec = (const float*)d_in[9];
    const float* alpha_dot  = (const float*)d_in[10];
    const float* alpha_norm = (const float*)d_in[11];
    const float* Wg = (const float*)d_in[12];
    const float* bg = (const float*)d_in[13];

    float* ws = (float*)d_ws;
    float* vec_dot  = ws;              // 1048576
    float* vec_norm = ws + 1048576;    // 1048576
    float* gate     = ws + 2097152;    // 1048576
    short* sb = (short*)(ws + 3145728);
    short* xs_bf   = sb;               // 1048576
    short* vec_bf  = sb + 1048576;     // 3145728 (3 planes x 4096 x 256)
    short* inv_bf  = sb + 4194304;     // 2097152
    short* xout_bf = sb + 6291456;     // 1048576
    short* Q_bf    = sb + 7340032;     // 1048576
    short* K_bf    = sb + 8388608;     // 1048576
    short* V_bf    = sb + 9437184;     // 1048576
    short* WqkvT   = sb + 10485760;    // 196608
    short* WvecT   = sb + 10682368;    // 131072
    short* WgT     = sb + 10813440;    // 131072
    short* WoT     = sb + 10944512;    // 196608

    float* out = (float*)d_out;
    float* attnw = out + (size_t)Bc * Nn * 4 * Hh;  // offset 4,194,304

    castx_kernel<<<4096, 256, 0, stream>>>(x, alpha_norm, xs_bf, vec_bf, vec_norm, inv_bf);
    castw_kernel<<<640, 256, 0, stream>>>(Wq, Wk, Wv, Wvec, Wg, Wo,
                                          WqkvT, WvecT, WgT, WoT);
    gemm_qkv<<<dim3(64, 6), 256, 0, stream>>>(xs_bf, WqkvT, bq, bk, bv, Q_bf, K_bf, V_bf);
    gemm_vecdot<<<dim3(64, 4), 256, 0, stream>>>(vec_bf, WvecT, alpha_dot, vec_dot, inv_bf);
    gemm_gate<<<dim3(64, 4), 256, 0, stream>>>(inv_bf, WgT, bg, gate);
    attn_fused<<<1024, 256, 0, stream>>>(Q_bf, K_bf, V_bf, vec_bf, gate, x,
                                         attnw, out, xout_bf);
    gemm_outf<<<dim3(64, 4), 256, 0, stream>>>(xout_bf, WoT, bo, vec_dot, vec_norm, out);
}

// Round 5
// 146.292 us; speedup vs baseline: 5.6387x; 1.0447x over previous
//
#include <hip/hip_runtime.h>
#include <math.h>

#define Bc 2
#define Nn 2048
#define Hh 256
#define NH 8
#define Dd 32
#define WIN 32
#define WL 65
#define BN (Bc * Nn)   // 4096

typedef __attribute__((ext_vector_type(8))) short bf16x8;
typedef __attribute__((ext_vector_type(4))) float f32x4;

__device__ inline short f2bf(float f) {
    union { float f; unsigned u; } v; v.f = f;
    unsigned r = v.u + 0x7fffu + ((v.u >> 16) & 1u);
    return (short)(r >> 16);
}

// ---------------- merged cast kernel: x -> bf16 (+norm), weights -> bf16 B^T ------
// blocks [0,4096): castx; [4096,4736): castw
__global__ __launch_bounds__(256) void castxw_kernel(
    const float* __restrict__ x, const float* __restrict__ alpha_norm,
    const float* __restrict__ Wq, const float* __restrict__ Wk, const float* __restrict__ Wv,
    const float* __restrict__ Wvec, const float* __restrict__ Wg, const float* __restrict__ Wo,
    short* __restrict__ xs_bf, short* __restrict__ vec_bf,
    float* __restrict__ vec_norm, short* __restrict__ inv_bf,
    short* __restrict__ WqkvT, short* __restrict__ WvecT,
    short* __restrict__ WgT, short* __restrict__ WoT) {
    __shared__ float Ts[32][33];
    if (blockIdx.x < 4096) {
        const int idx = blockIdx.x * 256 + threadIdx.x;
        const int bn = idx >> 8, ch = idx & 255;
        const size_t base = (size_t)bn * 1024 + ch;
        const float xs = x[base];
        const float v0 = x[base + 256], v1 = x[base + 512], v2 = x[base + 768];
        xs_bf[(size_t)bn * 256 + ch] = f2bf(xs);
        vec_bf[((size_t)0 * BN + bn) * 256 + ch] = f2bf(v0);
        vec_bf[((size_t)1 * BN + bn) * 256 + ch] = f2bf(v1);
        vec_bf[((size_t)2 * BN + bn) * 256 + ch] = f2bf(v2);
        const float nrm = sqrtf(v0 * v0 + v1 * v1 + v2 * v2);
        vec_norm[(size_t)bn * 256 + ch] = nrm;
        inv_bf[(size_t)bn * 512 + 256 + ch] = f2bf(alpha_norm[0] * nrm);
        return;
    }
    const int t = threadIdx.x;
    const int cc = t & 31, r0 = t >> 5;
    const int id = blockIdx.x - 4096;
    const float* W; int ldw; short* WT; int ldwt; int n0s, k0, n0d;
    if (id < 192) {            // [Wq|Wk|Wv] 256x768 -> WqkvT 768x256
        const int tn = id >> 3, tk = id & 7, sel = tn >> 3;
        W = sel == 0 ? Wq : (sel == 1 ? Wk : Wv); ldw = 256;
        n0s = (tn & 7) * 32; k0 = tk * 32; WT = WqkvT; ldwt = 256; n0d = tn * 32;
    } else if (id < 320) {     // Wvec 256x512 -> WvecT 512x256
        const int id2 = id - 192, tn = id2 >> 3, tk = id2 & 7;
        W = Wvec; ldw = 512; n0s = tn * 32; k0 = tk * 32; WT = WvecT; ldwt = 256; n0d = n0s;
    } else if (id < 448) {     // Wg 512x256 -> WgT 256x512
        const int id3 = id - 320, tn = id3 >> 4, tk = id3 & 15;
        W = Wg; ldw = 256; n0s = tn * 32; k0 = tk * 32; WT = WgT; ldwt = 512; n0d = n0s;
    } else {                   // Wo 256x768 -> WoT 768x256
        const int id4 = id - 448, tn = id4 >> 3, tk = id4 & 7;
        W = Wo; ldw = 768; n0s = tn * 32; k0 = tk * 32; WT = WoT; ldwt = 256; n0d = n0s;
    }
#pragma unroll
    for (int p = 0; p < 4; ++p) {
        const int rr = r0 + p * 8;
        Ts[rr][cc] = W[(size_t)(k0 + rr) * ldw + n0s + cc];
    }
    __syncthreads();
#pragma unroll
    for (int p = 0; p < 4; ++p) {
        const int rr = r0 + p * 8;
        WT[(size_t)(n0d + rr) * ldwt + k0 + cc] = f2bf(Ts[cc][rr]);
    }
}

// ---------------- shared MFMA mainloop, register-prefetch pipelined ----------------
template<int NT>
__device__ inline void gemm_tiles(const short* __restrict__ A, const short* __restrict__ BT,
                                  int K, int row0, int col0,
                                  short* As, short* Bs, f32x4 acc[2][NT]) {
    const int t = threadIdx.x;
    const int lane = t & 63, wid = t >> 6;
    const int wm = wid & 1, wn = wid >> 1;
    const int quad = lane >> 4, lm = lane & 15;
    const int srow = t >> 2, scg = (t & 3) * 8;
#pragma unroll
    for (int mt = 0; mt < 2; ++mt)
#pragma unroll
        for (int nt = 0; nt < NT; ++nt) {
            f32x4 z = {0.f, 0.f, 0.f, 0.f};
            acc[mt][nt] = z;
        }
    bf16x8 pa = *(const bf16x8*)&A[(size_t)(row0 + srow) * K + scg];
    bf16x8 pb[NT / 2];
#pragma unroll
    for (int p = 0; p < NT / 2; ++p) {
        const int idx = t + p * 256;
        pb[p] = *(const bf16x8*)&BT[(size_t)(col0 + (idx >> 2)) * K + (idx & 3) * 8];
    }
    for (int k0 = 0; k0 < K; k0 += 32) {
        *(bf16x8*)&As[srow * 40 + scg] = pa;
#pragma unroll
        for (int p = 0; p < NT / 2; ++p) {
            const int idx = t + p * 256;
            *(bf16x8*)&Bs[(idx >> 2) * 40 + (idx & 3) * 8] = pb[p];
        }
        __syncthreads();
        if (k0 + 32 < K) {
            pa = *(const bf16x8*)&A[(size_t)(row0 + srow) * K + k0 + 32 + scg];
#pragma unroll
            for (int p = 0; p < NT / 2; ++p) {
                const int idx = t + p * 256;
                pb[p] = *(const bf16x8*)&BT[(size_t)(col0 + (idx >> 2)) * K + k0 + 32 + (idx & 3) * 8];
            }
        }
        bf16x8 af[2], bfr[NT];
#pragma unroll
        for (int mt = 0; mt < 2; ++mt)
            af[mt] = *(bf16x8*)&As[(wm * 32 + mt * 16 + lm) * 40 + quad * 8];
#pragma unroll
        for (int nt = 0; nt < NT; ++nt)
            bfr[nt] = *(bf16x8*)&Bs[(wn * NT * 16 + nt * 16 + lm) * 40 + quad * 8];
#pragma unroll
        for (int mt = 0; mt < 2; ++mt)
#pragma unroll
            for (int nt = 0; nt < NT; ++nt)
                acc[mt][nt] = __builtin_amdgcn_mfma_f32_16x16x32_bf16(
                    af[mt], bfr[nt], acc[mt][nt], 0, 0, 0);
        __syncthreads();
    }
}

// ---------------- GEMM 1: qkv -> bf16 Q,K,V ----------------
__global__ __launch_bounds__(256) void gemm_qkv(
    const short* __restrict__ A, const short* __restrict__ BT,
    const float* __restrict__ bq, const float* __restrict__ bk, const float* __restrict__ bv,
    short* __restrict__ Qb, short* __restrict__ Kb, short* __restrict__ Vb) {
    __shared__ short As[64 * 40];
    __shared__ short Bs[128 * 40];
    f32x4 acc[2][4];
    const int row0 = blockIdx.x * 64, col0 = blockIdx.y * 128;
    gemm_tiles<4>(A, BT, 256, row0, col0, As, Bs, acc);
    const int lane = threadIdx.x & 63, wid = threadIdx.x >> 6;
    const int wm = wid & 1, wn = wid >> 1, quad = lane >> 4, lm = lane & 15;
    const int chunk = col0 >> 8;
    short* dst = chunk == 0 ? Qb : (chunk == 1 ? Kb : Vb);
    const float* bias = chunk == 0 ? bq : (chunk == 1 ? bk : bv);
#pragma unroll
    for (int mt = 0; mt < 2; ++mt)
#pragma unroll
        for (int nt = 0; nt < 4; ++nt) {
            const int col = col0 + wn * 64 + nt * 16 + lm;
            const int cm = col & 255;
            const float bb = bias[cm];
#pragma unroll
            for (int r = 0; r < 4; ++r) {
                const int row = row0 + wm * 32 + mt * 16 + quad * 4 + r;
                dst[(size_t)row * 256 + cm] = f2bf(acc[mt][nt][r] + bb);
            }
        }
}

// ---------------- GEMM 2: vec_proj + fused vec_dot (tile 64 x 32) ----------------
// grid (64, 8); waves 2(m: 32 rows) x 2(n: 16 cols); pipelined.
__global__ __launch_bounds__(256) void gemm_vecdot(
    const short* __restrict__ A, const short* __restrict__ BT,
    const float* __restrict__ alpha_dot,
    float* __restrict__ vec_dot, short* __restrict__ inv_bf) {
    __shared__ short As[3][64 * 40];
    __shared__ short Bs[2][32 * 40];
    const int row0 = blockIdx.x * 64, ch0 = blockIdx.y * 32;
    const int t = threadIdx.x, lane = t & 63, wid = t >> 6;
    const int wm = wid & 1, wn = wid >> 1, quad = lane >> 4, lm = lane & 15;
    const int srow = t >> 2, scg = (t & 3) * 8;
    const int bh_ = t >> 7, bc = (t >> 2) & 31, bcg = (t & 3) * 8;  // B: h, col, k-group
    f32x4 acc[3][2][2];  // [plane][half][mt]
#pragma unroll
    for (int p = 0; p < 3; ++p)
#pragma unroll
        for (int h = 0; h < 2; ++h)
#pragma unroll
            for (int mt = 0; mt < 2; ++mt) {
                f32x4 z = {0.f, 0.f, 0.f, 0.f};
                acc[p][h][mt] = z;
            }
    bf16x8 pa[3], pb;
#pragma unroll
    for (int p = 0; p < 3; ++p)
        pa[p] = *(const bf16x8*)&A[((size_t)p * BN + row0 + srow) * 256 + scg];
    pb = *(const bf16x8*)&BT[(size_t)(bh_ * 256 + ch0 + bc) * 256 + bcg];
    for (int k0 = 0; k0 < 256; k0 += 32) {
#pragma unroll
        for (int p = 0; p < 3; ++p)
            *(bf16x8*)&As[p][srow * 40 + scg] = pa[p];
        *(bf16x8*)&Bs[bh_][bc * 40 + bcg] = pb;
        __syncthreads();
        if (k0 + 32 < 256) {
#pragma unroll
            for (int p = 0; p < 3; ++p)
                pa[p] = *(const bf16x8*)&A[((size_t)p * BN + row0 + srow) * 256 + k0 + 32 + scg];
            pb = *(const bf16x8*)&BT[(size_t)(bh_ * 256 + ch0 + bc) * 256 + k0 + 32 + bcg];
        }
        bf16x8 af[3][2], bfr[2];
#pragma unroll
        for (int p = 0; p < 3; ++p)
#pragma unroll
            for (int mt = 0; mt < 2; ++mt)
                af[p][mt] = *(bf16x8*)&As[p][(wm * 32 + mt * 16 + lm) * 40 + quad * 8];
#pragma unroll
        for (int h = 0; h < 2; ++h)
            bfr[h] = *(bf16x8*)&Bs[h][(wn * 16 + lm) * 40 + quad * 8];
#pragma unroll
        for (int p = 0; p < 3; ++p)
#pragma unroll
            for (int h = 0; h < 2; ++h)
#pragma unroll
                for (int mt = 0; mt < 2; ++mt)
                    acc[p][h][mt] = __builtin_amdgcn_mfma_f32_16x16x32_bf16(
                        af[p][mt], bfr[h], acc[p][h][mt], 0, 0, 0);
        __syncthreads();
    }
    const float ad = alpha_dot[0];
#pragma unroll
    for (int mt = 0; mt < 2; ++mt) {
        const int col = ch0 + wn * 16 + lm;
#pragma unroll
        for (int r = 0; r < 4; ++r) {
            const int row = row0 + wm * 32 + mt * 16 + quad * 4 + r;
            float dot = 0.f;
#pragma unroll
            for (int p = 0; p < 3; ++p)
                dot = fmaf(acc[p][0][mt][r], acc[p][1][mt][r], dot);
            vec_dot[(size_t)row * 256 + col] = dot;
            inv_bf[(size_t)row * 512 + col] = f2bf(ad * dot);
        }
    }
}

// ---------------- GEMM 3: gate ----------------
__global__ __launch_bounds__(256) void gemm_gate(
    const short* __restrict__ A, const short* __restrict__ BT,
    const float* __restrict__ bg, float* __restrict__ gate) {
    __shared__ short As[64 * 40];
    __shared__ short Bs[64 * 40];
    f32x4 acc[2][2];
    const int row0 = blockIdx.x * 64, col0 = blockIdx.y * 64;
    gemm_tiles<2>(A, BT, 512, row0, col0, As, Bs, acc);
    const int lane = threadIdx.x & 63, wid = threadIdx.x >> 6;
    const int wm = wid & 1, wn = wid >> 1, quad = lane >> 4, lm = lane & 15;
#pragma unroll
    for (int mt = 0; mt < 2; ++mt)
#pragma unroll
        for (int nt = 0; nt < 2; ++nt) {
            const int col = col0 + wn * 32 + nt * 16 + lm;
            const float bb = bg[col];
#pragma unroll
            for (int r = 0; r < 4; ++r) {
                const int row = row0 + wm * 32 + mt * 16 + quad * 4 + r;
                const float z = acc[mt][nt][r] + bb;
                gate[(size_t)row * 256 + col] = 1.f / (1.f + __expf(-z));
            }
        }
}

// ---------------- fused attention v2: register softmax, 3 blocks/CU ----------------
__global__ __launch_bounds__(256) void attn_fused(
    const short* __restrict__ Qb, const short* __restrict__ Kb,
    const short* __restrict__ Vb, const short* __restrict__ vec_bf,
    const float* __restrict__ gate, const float* __restrict__ x,
    float* __restrict__ attnw, float* __restrict__ out, short* __restrict__ xout_bf) {
    const int bh = blockIdx.x >> 6, tile = blockIdx.x & 63;
    const int b = bh >> 3, hd = bh & 7;
    const int i0 = tile * 32;
    const int t = threadIdx.x, lane = t & 63, wid = t >> 6;
    const int wm = wid & 1, wn = wid >> 1, quad = lane >> 4, lm = lane & 15;

    __shared__ __align__(16) short Qs[32 * 40];    // i, d
    __shared__ __align__(16) short Ks[96 * 40];    // j, d (OOB rows = 0)
    __shared__ __align__(16) short Pb[32 * 104];   // i, jr bf16 weights (band, else 0)
    __shared__ __align__(16) short St[128 * 104];  // dim, jr (S transposed)

    // zero Pb band matrix
    for (int idx = t; idx < 32 * 104 / 2; idx += 256) ((int*)Pb)[idx] = 0;
    // stage Q (32 x 32 bf16)
    if (t < 128) {
        const int row = t >> 2, cg = t & 3;
        *(bf16x8*)&Qs[row * 40 + cg * 8] =
            *(const bf16x8*)&Qb[((size_t)(b * Nn + i0 + row)) * 256 + hd * 32 + cg * 8];
    }
    // stage K (96 x 32 bf16, halo, OOB -> 0)
#pragma unroll
    for (int kk = 0; kk < 2; ++kk) {
        const int idx = t + kk * 256;
        if (idx < 384) {
            const int row = idx >> 2, cg = idx & 3;
            const int j = i0 - WIN + row;
            bf16x8 kv = {0, 0, 0, 0, 0, 0, 0, 0};
            if (j >= 0 && j < Nn)
                kv = *(const bf16x8*)&Kb[((size_t)(b * Nn + j)) * 256 + hd * 32 + cg * 8];
            *(bf16x8*)&Ks[row * 40 + cg * 8] = kv;
        }
    }
    // stage S^T (128 dims x 96 jr): V dims 0-31, vec dims 32-127
    {
        const int chunk = t >> 4, j0 = t & 15;
#pragma unroll
        for (int it = 0; it < 6; ++it) {
            const int jr = j0 + it * 16;
            const int j = i0 - WIN + jr;
            bf16x8 val = {0, 0, 0, 0, 0, 0, 0, 0};
            if (j >= 0 && j < Nn) {
                if (chunk < 4)
                    val = *(const bf16x8*)&Vb[((size_t)(b * Nn + j)) * 256 + hd * 32 + chunk * 8];
                else {
                    const int vc = (chunk - 4) >> 2, d0 = ((chunk - 4) & 3) * 8;
                    val = *(const bf16x8*)&vec_bf[((size_t)vc * BN + b * Nn + j) * 256 + hd * 32 + d0];
                }
            }
#pragma unroll
            for (int u = 0; u < 8; ++u) St[(chunk * 8 + u) * 104 + jr] = val[u];
        }
    }
    __syncthreads();

    // scores + softmax, fully in-register: wave 0 -> rows 0-15, wave 1 -> rows 16-31
    if (wid < 2) {
        const int il0 = wid * 16;
        const bf16x8 aq = *(bf16x8*)&Qs[(il0 + lm) * 40 + quad * 8];
        f32x4 c[6];
#pragma unroll
        for (int nt = 0; nt < 6; ++nt) {
            const bf16x8 bk = *(bf16x8*)&Ks[(nt * 16 + lm) * 40 + quad * 8];
            f32x4 z = {0.f, 0.f, 0.f, 0.f};
            c[nt] = __builtin_amdgcn_mfma_f32_16x16x32_bf16(aq, bk, z, 0, 0, 0);
        }
        // lane holds rows il = il0 + quad*4 + r, cols jr = nt*16 + lm; w = jr - il
        float mx[4] = {-1e30f, -1e30f, -1e30f, -1e30f};
#pragma unroll
        for (int nt = 0; nt < 6; ++nt)
#pragma unroll
            for (int r = 0; r < 4; ++r) {
                const int il = il0 + quad * 4 + r;
                const int w = nt * 16 + lm - il;
                const float v = (w >= 0 && w <= 64)
                    ? c[nt][r] * 0.17677669529663687f : -1e30f;
                c[nt][r] = v;
                mx[r] = fmaxf(mx[r], v);
            }
#pragma unroll
        for (int off = 1; off < 16; off <<= 1)
#pragma unroll
            for (int r = 0; r < 4; ++r) mx[r] = fmaxf(mx[r], __shfl_xor(mx[r], off, 64));
        float sm[4] = {0.f, 0.f, 0.f, 0.f};
#pragma unroll
        for (int nt = 0; nt < 6; ++nt)
#pragma unroll
            for (int r = 0; r < 4; ++r) {
                const int il = il0 + quad * 4 + r;
                const int w = nt * 16 + lm - il;
                const float e = (w >= 0 && w <= 64) ? __expf(c[nt][r] - mx[r]) : 0.f;
                c[nt][r] = e;
                sm[r] += e;
            }
#pragma unroll
        for (int off = 1; off < 16; off <<= 1)
#pragma unroll
            for (int r = 0; r < 4; ++r) sm[r] += __shfl_xor(sm[r], off, 64);
        float inv[4];
#pragma unroll
        for (int r = 0; r < 4; ++r) inv[r] = 1.f / sm[r];
#pragma unroll
        for (int nt = 0; nt < 6; ++nt)
#pragma unroll
            for (int r = 0; r < 4; ++r) {
                const int il = il0 + quad * 4 + r;
                const int jr = nt * 16 + lm;
                const int w = jr - il;
                if (w >= 0 && w <= 64) {
                    const float pw = c[nt][r] * inv[r];
                    attnw[((size_t)bh * Nn + (i0 + il)) * WL + w] = pw;
                    Pb[il * 104 + jr] = f2bf(pw);
                }
            }
    }
    __syncthreads();

    // PV: 32i x 128dim, K=96: per wave 1 m-tile x 4 n-tiles x 3 k-steps
    f32x4 acc[4];
#pragma unroll
    for (int nt = 0; nt < 4; ++nt) {
        f32x4 z = {0.f, 0.f, 0.f, 0.f};
        acc[nt] = z;
    }
#pragma unroll
    for (int ks = 0; ks < 3; ++ks) {
        const bf16x8 ap = *(bf16x8*)&Pb[(wm * 16 + lm) * 104 + ks * 32 + quad * 8];
#pragma unroll
        for (int nt = 0; nt < 4; ++nt) {
            const bf16x8 bs = *(bf16x8*)&St[(wn * 64 + nt * 16 + lm) * 104 + ks * 32 + quad * 8];
            acc[nt] = __builtin_amdgcn_mfma_f32_16x16x32_bf16(ap, bs, acc[nt], 0, 0, 0);
        }
    }
    // epilogue: dims<32 -> xout_bf; dims>=32 -> gated vec output directly
#pragma unroll
    for (int nt = 0; nt < 4; ++nt) {
        const int dim = wn * 64 + nt * 16 + lm;
#pragma unroll
        for (int r = 0; r < 4; ++r) {
            const int i = wm * 16 + quad * 4 + r;
            const size_t bn = (size_t)(b * Nn + i0 + i);
            if (dim < 32) {
                xout_bf[bn * 256 + hd * 32 + dim] = f2bf(acc[nt][r]);
            } else {
                const int dm = dim - 32, c = dm >> 5, dd = dm & 31;
                const int ch = hd * 32 + dd;
                const float g = gate[bn * 256 + ch];
                const size_t off = bn * 1024 + (1 + c) * 256 + ch;
                out[off] = fmaf(g, acc[nt][r], x[off]);
            }
        }
    }
}

// ---------------- GEMM 4: output projection + scalar combine, pipelined ----------
__global__ __launch_bounds__(256) void gemm_outf(
    const short* __restrict__ A, const short* __restrict__ BT,
    const float* __restrict__ bo,
    const float* __restrict__ vec_dot, const float* __restrict__ vec_norm,
    float* __restrict__ out) {
    __shared__ short As[64 * 40];
    __shared__ short Bs[3][64 * 40];
    const int row0 = blockIdx.x * 64, ch0 = blockIdx.y * 64;
    const int t = threadIdx.x, lane = t & 63, wid = t >> 6;
    const int wm = wid & 1, wn = wid >> 1, quad = lane >> 4, lm = lane & 15;
    const int srow = t >> 2, scg = (t & 3) * 8;
    f32x4 acc[3][2][2];
#pragma unroll
    for (int p = 0; p < 3; ++p)
#pragma unroll
        for (int mt = 0; mt < 2; ++mt)
#pragma unroll
            for (int nt = 0; nt < 2; ++nt) {
                f32x4 z = {0.f, 0.f, 0.f, 0.f};
                acc[p][mt][nt] = z;
            }
    bf16x8 pa, pb[3];
    pa = *(const bf16x8*)&A[(size_t)(row0 + srow) * 256 + scg];
#pragma unroll
    for (int p = 0; p < 3; ++p)
        pb[p] = *(const bf16x8*)&BT[(size_t)(p * 256 + ch0 + srow) * 256 + scg];
    for (int k0 = 0; k0 < 256; k0 += 32) {
        *(bf16x8*)&As[srow * 40 + scg] = pa;
#pragma unroll
        for (int p = 0; p < 3; ++p)
            *(bf16x8*)&Bs[p][srow * 40 + scg] = pb[p];
        __syncthreads();
        if (k0 + 32 < 256) {
            pa = *(const bf16x8*)&A[(size_t)(row0 + srow) * 256 + k0 + 32 + scg];
#pragma unroll
            for (int p = 0; p < 3; ++p)
                pb[p] = *(const bf16x8*)&BT[(size_t)(p * 256 + ch0 + srow) * 256 + k0 + 32 + scg];
        }
        bf16x8 af[2], bfr[3][2];
#pragma unroll
        for (int mt = 0; mt < 2; ++mt)
            af[mt] = *(bf16x8*)&As[(wm * 32 + mt * 16 + lm) * 40 + quad * 8];
#pragma unroll
        for (int p = 0; p < 3; ++p)
#pragma unroll
            for (int nt = 0; nt < 2; ++nt)
                bfr[p][nt] = *(bf16x8*)&Bs[p][(wn * 32 + nt * 16 + lm) * 40 + quad * 8];
#pragma unroll
        for (int p = 0; p < 3; ++p)
#pragma unroll
            for (int mt = 0; mt < 2; ++mt)
#pragma unroll
                for (int nt = 0; nt < 2; ++nt)
                    acc[p][mt][nt] = __builtin_amdgcn_mfma_f32_16x16x32_bf16(
                        af[mt], bfr[p][nt], acc[p][mt][nt], 0, 0, 0);
        __syncthreads();
    }
#pragma unroll
    for (int mt = 0; mt < 2; ++mt)
#pragma unroll
        for (int nt = 0; nt < 2; ++nt) {
            const int col = ch0 + wn * 32 + nt * 16 + lm;
            const float b1 = bo[col], b2 = bo[256 + col], b3 = bo[512 + col];
#pragma unroll
            for (int r = 0; r < 4; ++r) {
                const int row = row0 + wm * 32 + mt * 16 + quad * 4 + r;
                const float o1 = acc[0][mt][nt][r] + b1;
                const float o2 = acc[1][mt][nt][r] + b2;
                const float o3 = acc[2][mt][nt][r] + b3;
                const float vd = vec_dot[(size_t)row * 256 + col];
                const float vn = vec_norm[(size_t)row * 256 + col];
                out[(size_t)row * 1024 + col] = vd * o1 + vn * o2 + o3;
            }
        }
}

extern "C" void kernel_launch(void* const* d_in, const int* in_sizes, int n_in,
                              void* d_out, int out_size, void* d_ws, size_t ws_size,
                              hipStream_t stream) {
    const float* x  = (const float*)d_in[0];
    const float* Wq = (const float*)d_in[1];
    const float* bq = (const float*)d_in[2];
    const float* Wk = (const float*)d_in[3];
    const float* bk = (const float*)d_in[4];
    const float* Wv = (const float*)d_in[5];
    const float* bv = (const float*)d_in[6];
    const float* Wo = (const float*)d_in[7];
    const float* bo = (const float*)d_in[8];
    const float* Wvec = (const float*)d_in[9];
    const float* alpha_dot  = (const float*)d_in[10];
    const float* alpha_norm = (const float*)d_in[11];
    const float* Wg = (const float*)d_in[12];
    const float* bg = (const float*)d_in[13];

    float* ws = (float*)d_ws;
    float* vec_dot  = ws;              // 1048576
    float* vec_norm = ws + 1048576;    // 1048576
    float* gate     = ws + 2097152;    // 1048576
    short* sb = (short*)(ws + 3145728);
    short* xs_bf   = sb;               // 1048576
    short* vec_bf  = sb + 1048576;     // 3145728 (3 planes x 4096 x 256)
    short* inv_bf  = sb + 4194304;     // 2097152
    short* xout_bf = sb + 6291456;     // 1048576
    short* Q_bf    = sb + 7340032;     // 1048576
    short* K_bf    = sb + 8388608;     // 1048576
    short* V_bf    = sb + 9437184;     // 1048576
    short* WqkvT   = sb + 10485760;    // 196608
    short* WvecT   = sb + 10682368;    // 131072
    short* WgT     = sb + 10813440;    // 131072
    short* WoT     = sb + 10944512;    // 196608

    float* out = (float*)d_out;
    float* attnw = out + (size_t)Bc * Nn * 4 * Hh;  // offset 4,194,304

    castxw_kernel<<<4736, 256, 0, stream>>>(x, alpha_norm, Wq, Wk, Wv, Wvec, Wg, Wo,
                                            xs_bf, vec_bf, vec_norm, inv_bf,
                                            WqkvT, WvecT, WgT, WoT);
    gemm_qkv<<<dim3(64, 6), 256, 0, stream>>>(xs_bf, WqkvT, bq, bk, bv, Q_bf, K_bf, V_bf);
    gemm_vecdot<<<dim3(64, 8), 256, 0, stream>>>(vec_bf, WvecT, alpha_dot, vec_dot, inv_bf);
    gemm_gate<<<dim3(64, 4), 256, 0, stream>>>(inv_bf, WgT, bg, gate);
    attn_fused<<<1024, 256, 0, stream>>>(Q_bf, K_bf, V_bf, vec_bf, gate, x,
                                         attnw, out, xout_bf);
    gemm_outf<<<dim3(64, 4), 256, 0, stream>>>(xout_bf, WoT, bo, vec_dot, vec_norm, out);
}